// Round 1
// baseline (5165.101 us; speedup 1.0000x reference)
//
#include <hip/hip_runtime.h>
#include <math.h>

// Dims fixed by the reference problem.
#define N_TOK 8192
#define D_IN  1024
#define D_QK  128

// ---------------------------------------------------------------------------
// Generic f32 GEMM: C[M][N] = A[M][K] * B[N][K]^T   (all row-major)
// 64x64 tile, BK=16, 256 threads, each thread 4x4 outputs.
// LDS is stored k-major (As[kk][row]) so the inner loop is two ds_read_b128.
// ---------------------------------------------------------------------------
__global__ __launch_bounds__(256) void gemm_abt(const float* __restrict__ A,
                                                const float* __restrict__ B,
                                                float* __restrict__ C,
                                                int M, int N, int K) {
  __shared__ float As[16][68];
  __shared__ float Bs[16][68];
  const int tid = threadIdx.x;
  const int m0 = blockIdx.y * 64;
  const int n0 = blockIdx.x * 64;
  const int tr = tid >> 4;    // 0..15 -> output rows tr*4..tr*4+3
  const int tc = tid & 15;    // 0..15 -> output cols tc*4..tc*4+3
  const int srow = tid >> 2;  // 0..63 staging row
  const int sk = tid & 3;     // 0..3  staging k-seg (4 floats)
  float acc[4][4] = {};
  for (int kt = 0; kt < K; kt += 16) {
    const float4 a = *(const float4*)&A[(size_t)(m0 + srow) * K + kt + sk * 4];
    const float4 b = *(const float4*)&B[(size_t)(n0 + srow) * K + kt + sk * 4];
    As[sk * 4 + 0][srow] = a.x; As[sk * 4 + 1][srow] = a.y;
    As[sk * 4 + 2][srow] = a.z; As[sk * 4 + 3][srow] = a.w;
    Bs[sk * 4 + 0][srow] = b.x; Bs[sk * 4 + 1][srow] = b.y;
    Bs[sk * 4 + 2][srow] = b.z; Bs[sk * 4 + 3][srow] = b.w;
    __syncthreads();
#pragma unroll
    for (int kk = 0; kk < 16; ++kk) {
      const float4 av = *(const float4*)&As[kk][tr * 4];
      const float4 bv = *(const float4*)&Bs[kk][tc * 4];
      acc[0][0] += av.x * bv.x; acc[0][1] += av.x * bv.y;
      acc[0][2] += av.x * bv.z; acc[0][3] += av.x * bv.w;
      acc[1][0] += av.y * bv.x; acc[1][1] += av.y * bv.y;
      acc[1][2] += av.y * bv.z; acc[1][3] += av.y * bv.w;
      acc[2][0] += av.z * bv.x; acc[2][1] += av.z * bv.y;
      acc[2][2] += av.z * bv.z; acc[2][3] += av.z * bv.w;
      acc[3][0] += av.w * bv.x; acc[3][1] += av.w * bv.y;
      acc[3][2] += av.w * bv.z; acc[3][3] += av.w * bv.w;
    }
    __syncthreads();
  }
#pragma unroll
  for (int i = 0; i < 4; ++i) {
    float4 o;
    o.x = acc[i][0]; o.y = acc[i][1]; o.z = acc[i][2]; o.w = acc[i][3];
    *(float4*)&C[(size_t)(m0 + tr * 4 + i) * N + n0 + tc * 4] = o;
  }
}

// ---------------------------------------------------------------------------
// Flash attention (f32): sa = softmax(scale * q k^T) v
// grid = 256 blocks (32 q-rows each), 512 threads (8 waves).
// Per tile of 128 k-rows:
//   A) scores: thread (rg,jg) computes 2 rows x 4 cols dots (q from LDS
//      broadcast, k from global/L2), writes transposed ps[j][r] (*scale)
//   B) online softmax: wave w owns rows w*4..w*4+3, 64-lane shfl reduce
//   C) PV: wave w owns v-cols w*128..w*128+127; acc[32 rows][2 cols]/lane;
//      p read as b128 broadcast from ps[j][.]; v read coalesced float2.
// ---------------------------------------------------------------------------
__global__ __launch_bounds__(512) void flash_attn(const float* __restrict__ q,
                                                  const float* __restrict__ kmat,
                                                  const float* __restrict__ v,
                                                  float* __restrict__ sa) {
  __shared__ float qs[32 * 128];
  __shared__ float ps[128 * 36];  // stride 36 floats = 144B (16B-aligned rows)
  __shared__ float mrun[32];
  __shared__ float lrun[32];
  __shared__ float facl[32];
  const int tid = threadIdx.x;
  const int q0 = blockIdx.x * 32;

  {  // stage q tile: 32x128 f32
    const float4* q4 = (const float4*)q;
    float4* qs4 = (float4*)qs;
#pragma unroll
    for (int i = 0; i < 2; ++i) {
      const int e = i * 512 + tid;
      qs4[e] = q4[(size_t)(q0 + (e >> 5)) * 32 + (e & 31)];
    }
  }
  if (tid < 32) { mrun[tid] = -INFINITY; lrun[tid] = 0.0f; }
  __syncthreads();

  const int rg = tid >> 5;  // 0..15: score rows rg*2, rg*2+1
  const int jg = tid & 31;  // score cols jg + 32*jj
  const int w = tid >> 6;   // wave 0..7
  const int l = tid & 63;   // lane
  const float scale = 11.31370849898476f;  // sqrt(128)

  float acc[32][2];
#pragma unroll
  for (int r = 0; r < 32; ++r) { acc[r][0] = 0.0f; acc[r][1] = 0.0f; }

  for (int t = 0; t < 64; ++t) {
    const int t0 = t * 128;
    // ---- Phase A: scores ----
    float s0[4] = {}, s1[4] = {};
    {
      const float4* k4 = (const float4*)kmat;
      const float4* qs4 = (const float4*)qs;
#pragma unroll 4
      for (int c = 0; c < 32; ++c) {
        const float4 qa = qs4[(rg * 2 + 0) * 32 + c];
        const float4 qb = qs4[(rg * 2 + 1) * 32 + c];
#pragma unroll
        for (int jj = 0; jj < 4; ++jj) {
          const float4 kv = k4[(size_t)(t0 + jg + 32 * jj) * 32 + c];
          s0[jj] += qa.x * kv.x + qa.y * kv.y + qa.z * kv.z + qa.w * kv.w;
          s1[jj] += qb.x * kv.x + qb.y * kv.y + qb.z * kv.z + qb.w * kv.w;
        }
      }
    }
#pragma unroll
    for (int jj = 0; jj < 4; ++jj) {
      ps[(jg + 32 * jj) * 36 + rg * 2 + 0] = s0[jj] * scale;
      ps[(jg + 32 * jj) * 36 + rg * 2 + 1] = s1[jj] * scale;
    }
    __syncthreads();
    // ---- Phase B: online softmax (wave w -> rows w*4..w*4+3) ----
#pragma unroll
    for (int qq = 0; qq < 4; ++qq) {
      const int r = w * 4 + qq;
      float p0 = ps[l * 36 + r];
      float p1 = ps[(l + 64) * 36 + r];
      float mx = fmaxf(p0, p1);
#pragma unroll
      for (int off = 32; off > 0; off >>= 1) mx = fmaxf(mx, __shfl_xor(mx, off));
      const float mo = mrun[r];
      const float mn = fmaxf(mo, mx);
      const float e0 = __expf(p0 - mn);
      const float e1 = __expf(p1 - mn);
      float sm = e0 + e1;
#pragma unroll
      for (int off = 32; off > 0; off >>= 1) sm += __shfl_xor(sm, off);
      ps[l * 36 + r] = e0;
      ps[(l + 64) * 36 + r] = e1;
      if (l == 0) {
        const float fac = __expf(mo - mn);
        facl[r] = fac;
        mrun[r] = mn;
        lrun[r] = lrun[r] * fac + sm;
      }
    }
    __syncthreads();
    // ---- Phase C: rescale + PV ----
#pragma unroll
    for (int r = 0; r < 32; ++r) {
      const float f = facl[r];
      acc[r][0] *= f; acc[r][1] *= f;
    }
    {
      const float2* v2 = (const float2*)v;
      const size_t cbase = (size_t)w * 128 + l * 2;
      for (int j = 0; j < 128; ++j) {
        const float2 vv = v2[((size_t)(t0 + j) * 1024 + cbase) >> 1];
        const float4* prow = (const float4*)&ps[j * 36];
#pragma unroll
        for (int g = 0; g < 8; ++g) {
          const float4 p = prow[g];
          acc[4 * g + 0][0] += p.x * vv.x; acc[4 * g + 0][1] += p.x * vv.y;
          acc[4 * g + 1][0] += p.y * vv.x; acc[4 * g + 1][1] += p.y * vv.y;
          acc[4 * g + 2][0] += p.z * vv.x; acc[4 * g + 2][1] += p.z * vv.y;
          acc[4 * g + 3][0] += p.w * vv.x; acc[4 * g + 3][1] += p.w * vv.y;
        }
      }
    }
    __syncthreads();
  }
  // epilogue: divide by softmax denom, write sa
#pragma unroll
  for (int r = 0; r < 32; ++r) {
    const float inv = 1.0f / lrun[r];
    float2 o;
    o.x = acc[r][0] * inv;
    o.y = acc[r][1] * inv;
    *(float2*)&sa[(size_t)(q0 + r) * 1024 + w * 128 + l * 2] = o;
  }
}

// ---------------------------------------------------------------------------
// out = LayerNorm(a + b) over last dim (1024), no affine. One block per row.
// Safe to call with o == b (each element read+written by the same thread).
// ---------------------------------------------------------------------------
__global__ __launch_bounds__(256) void ln_add(const float* __restrict__ a,
                                              const float* __restrict__ b,
                                              float* __restrict__ o) {
  const int row = blockIdx.x;
  const int tid = threadIdx.x;
  const size_t base = (size_t)row * 256 + tid;  // float4 index
  const float4 av = ((const float4*)a)[base];
  const float4 bv = ((const float4*)b)[base];
  float4 y;
  y.x = av.x + bv.x; y.y = av.y + bv.y;
  y.z = av.z + bv.z; y.w = av.w + bv.w;
  float s1 = y.x + y.y + y.z + y.w;
  float s2 = y.x * y.x + y.y * y.y + y.z * y.z + y.w * y.w;
#pragma unroll
  for (int off = 32; off > 0; off >>= 1) {
    s1 += __shfl_xor(s1, off);
    s2 += __shfl_xor(s2, off);
  }
  __shared__ float r1[4];
  __shared__ float r2[4];
  if ((tid & 63) == 0) { r1[tid >> 6] = s1; r2[tid >> 6] = s2; }
  __syncthreads();
  s1 = r1[0] + r1[1] + r1[2] + r1[3];
  s2 = r2[0] + r2[1] + r2[2] + r2[3];
  const float mu = s1 * (1.0f / 1024.0f);
  const float var = s2 * (1.0f / 1024.0f) - mu * mu;
  const float rs = rsqrtf(var + 1e-5f);
  float4 ov;
  ov.x = (y.x - mu) * rs; ov.y = (y.y - mu) * rs;
  ov.z = (y.z - mu) * rs; ov.w = (y.w - mu) * rs;
  ((float4*)o)[base] = ov;
}

// ---------------------------------------------------------------------------
extern "C" void kernel_launch(void* const* d_in, const int* in_sizes, int n_in,
                              void* d_out, int out_size, void* d_ws, size_t ws_size,
                              hipStream_t stream) {
  const float* x  = (const float*)d_in[0];
  const float* Wq = (const float*)d_in[1];
  const float* Wk = (const float*)d_in[2];
  const float* Wv = (const float*)d_in[3];
  const float* Wl = (const float*)d_in[4];
  float* out = (float*)d_out;

  // workspace layout (floats): q(1M) k(1M) v(8M) sa(8M) h(8M) = 104.9 MB
  float* ws = (float*)d_ws;
  float* q  = ws;
  float* k  = q + (size_t)N_TOK * D_QK;
  float* v  = k + (size_t)N_TOK * D_QK;
  float* sa = v + (size_t)N_TOK * D_IN;
  float* h  = sa + (size_t)N_TOK * D_IN;

  // q = x Wq^T, k = x Wk^T   [8192,128]
  gemm_abt<<<dim3(D_QK / 64, N_TOK / 64), 256, 0, stream>>>(x, Wq, q, N_TOK, D_QK, D_IN);
  gemm_abt<<<dim3(D_QK / 64, N_TOK / 64), 256, 0, stream>>>(x, Wk, k, N_TOK, D_QK, D_IN);
  // v = x Wv^T   [8192,1024]
  gemm_abt<<<dim3(D_IN / 64, N_TOK / 64), 256, 0, stream>>>(x, Wv, v, N_TOK, D_IN, D_IN);
  // sa = softmax(scale q k^T) v
  flash_attn<<<N_TOK / 32, 512, 0, stream>>>(q, k, v, sa);
  // h = LN(x + sa)
  ln_add<<<N_TOK, 256, 0, stream>>>(x, sa, h);
  // out = h Wl^T (temp), then out = LN(sa + out)  (in-place safe)
  gemm_abt<<<dim3(D_IN / 64, N_TOK / 64), 256, 0, stream>>>(h, Wl, out, N_TOK, D_IN, D_IN);
  ln_add<<<N_TOK, 256, 0, stream>>>(sa, out, out);
}

// Round 2
// 1470.010 us; speedup vs baseline: 3.5136x; 3.5136x over previous
//
#include <hip/hip_runtime.h>
#include <hip/hip_bf16.h>
#include <math.h>

#define N_TOK 8192
#define D_IN  1024
#define D_QK  128

typedef short bf16x8 __attribute__((ext_vector_type(8)));
typedef float f32x4 __attribute__((ext_vector_type(4)));

static __device__ __forceinline__ ushort f2bf(float f) {
  __hip_bfloat16 b = __float2bfloat16(f);
  return *(ushort*)&b;
}
static __device__ __forceinline__ float bf2f(ushort u) {
  __hip_bfloat16 b = *(__hip_bfloat16*)&u;
  return __bfloat162float(b);
}

// ---------------------------------------------------------------------------
// Generic f32 GEMM: C[M][N] = A[M][K] * B[N][K]^T   (all row-major)
// ---------------------------------------------------------------------------
__global__ __launch_bounds__(256) void gemm_abt(const float* __restrict__ A,
                                                const float* __restrict__ B,
                                                float* __restrict__ C,
                                                int M, int N, int K) {
  __shared__ float As[16][68];
  __shared__ float Bs[16][68];
  const int tid = threadIdx.x;
  const int m0 = blockIdx.y * 64;
  const int n0 = blockIdx.x * 64;
  const int tr = tid >> 4;
  const int tc = tid & 15;
  const int srow = tid >> 2;
  const int sk = tid & 3;
  float acc[4][4] = {};
  for (int kt = 0; kt < K; kt += 16) {
    const float4 a = *(const float4*)&A[(size_t)(m0 + srow) * K + kt + sk * 4];
    const float4 b = *(const float4*)&B[(size_t)(n0 + srow) * K + kt + sk * 4];
    As[sk * 4 + 0][srow] = a.x; As[sk * 4 + 1][srow] = a.y;
    As[sk * 4 + 2][srow] = a.z; As[sk * 4 + 3][srow] = a.w;
    Bs[sk * 4 + 0][srow] = b.x; Bs[sk * 4 + 1][srow] = b.y;
    Bs[sk * 4 + 2][srow] = b.z; Bs[sk * 4 + 3][srow] = b.w;
    __syncthreads();
#pragma unroll
    for (int kk = 0; kk < 16; ++kk) {
      const float4 av = *(const float4*)&As[kk][tr * 4];
      const float4 bv = *(const float4*)&Bs[kk][tc * 4];
      acc[0][0] += av.x * bv.x; acc[0][1] += av.x * bv.y;
      acc[0][2] += av.x * bv.z; acc[0][3] += av.x * bv.w;
      acc[1][0] += av.y * bv.x; acc[1][1] += av.y * bv.y;
      acc[1][2] += av.y * bv.z; acc[1][3] += av.y * bv.w;
      acc[2][0] += av.z * bv.x; acc[2][1] += av.z * bv.y;
      acc[2][2] += av.z * bv.z; acc[2][3] += av.z * bv.w;
      acc[3][0] += av.w * bv.x; acc[3][1] += av.w * bv.y;
      acc[3][2] += av.w * bv.z; acc[3][3] += av.w * bv.w;
    }
    __syncthreads();
  }
#pragma unroll
  for (int i = 0; i < 4; ++i) {
    float4 o;
    o.x = acc[i][0]; o.y = acc[i][1]; o.z = acc[i][2]; o.w = acc[i][3];
    *(float4*)&C[(size_t)(m0 + tr * 4 + i) * N + n0 + tc * 4] = o;
  }
}

// Same GEMM, bf16 output (for the transposed v matrix).
__global__ __launch_bounds__(256) void gemm_abt_bf16(const float* __restrict__ A,
                                                     const float* __restrict__ B,
                                                     ushort* __restrict__ C,
                                                     int M, int N, int K) {
  __shared__ float As[16][68];
  __shared__ float Bs[16][68];
  const int tid = threadIdx.x;
  const int m0 = blockIdx.y * 64;
  const int n0 = blockIdx.x * 64;
  const int tr = tid >> 4;
  const int tc = tid & 15;
  const int srow = tid >> 2;
  const int sk = tid & 3;
  float acc[4][4] = {};
  for (int kt = 0; kt < K; kt += 16) {
    const float4 a = *(const float4*)&A[(size_t)(m0 + srow) * K + kt + sk * 4];
    const float4 b = *(const float4*)&B[(size_t)(n0 + srow) * K + kt + sk * 4];
    As[sk * 4 + 0][srow] = a.x; As[sk * 4 + 1][srow] = a.y;
    As[sk * 4 + 2][srow] = a.z; As[sk * 4 + 3][srow] = a.w;
    Bs[sk * 4 + 0][srow] = b.x; Bs[sk * 4 + 1][srow] = b.y;
    Bs[sk * 4 + 2][srow] = b.z; Bs[sk * 4 + 3][srow] = b.w;
    __syncthreads();
#pragma unroll
    for (int kk = 0; kk < 16; ++kk) {
      const float4 av = *(const float4*)&As[kk][tr * 4];
      const float4 bv = *(const float4*)&Bs[kk][tc * 4];
      acc[0][0] += av.x * bv.x; acc[0][1] += av.x * bv.y;
      acc[0][2] += av.x * bv.z; acc[0][3] += av.x * bv.w;
      acc[1][0] += av.y * bv.x; acc[1][1] += av.y * bv.y;
      acc[1][2] += av.y * bv.z; acc[1][3] += av.y * bv.w;
      acc[2][0] += av.z * bv.x; acc[2][1] += av.z * bv.y;
      acc[2][2] += av.z * bv.z; acc[2][3] += av.z * bv.w;
      acc[3][0] += av.w * bv.x; acc[3][1] += av.w * bv.y;
      acc[3][2] += av.w * bv.z; acc[3][3] += av.w * bv.w;
    }
    __syncthreads();
  }
#pragma unroll
  for (int i = 0; i < 4; ++i) {
    ushort4 o;
    o.x = f2bf(acc[i][0]); o.y = f2bf(acc[i][1]);
    o.z = f2bf(acc[i][2]); o.w = f2bf(acc[i][3]);
    *(ushort4*)&C[(size_t)(m0 + tr * 4 + i) * N + n0 + tc * 4] = o;
  }
}

// ---------------------------------------------------------------------------
// hi/lo bf16 split (with scale folded in): in*scale = hi + lo (to ~2^-17 rel)
// ---------------------------------------------------------------------------
__global__ __launch_bounds__(256) void split_hl(const float* __restrict__ in,
                                                ushort* __restrict__ hi,
                                                ushort* __restrict__ lo,
                                                float scale) {
  const int idx = blockIdx.x * 256 + threadIdx.x;
  const float4 v = ((const float4*)in)[idx];
  float f[4] = {v.x * scale, v.y * scale, v.z * scale, v.w * scale};
  ushort h[4], g[4];
#pragma unroll
  for (int i = 0; i < 4; ++i) {
    h[i] = f2bf(f[i]);
    g[i] = f2bf(f[i] - bf2f(h[i]));
  }
  ushort4 hv; hv.x = h[0]; hv.y = h[1]; hv.z = h[2]; hv.w = h[3];
  ushort4 gv; gv.x = g[0]; gv.y = g[1]; gv.z = g[2]; gv.w = g[3];
  ((ushort4*)hi)[idx] = hv;
  ((ushort4*)lo)[idx] = gv;
}

// ---------------------------------------------------------------------------
// MFMA flash attention: sa = softmax(q_scaled k^T) v
// 256 blocks x 512 threads (8 waves). QBLK=32 rows/block, KVBLK=128/tile.
// Scores via 3-MFMA hi/lo split (f32-accurate logits); PV in plain bf16.
// Wave w: score cols w*16..w*16+15; softmax rows w*4..w*4+3; PV cols w*128..
// P stored bf16 in LDS with XOR swizzle (byte ^= (row&7)<<4) -> conflict-free
// ds_read_b128 A-frags.
// ---------------------------------------------------------------------------
__global__ __launch_bounds__(512, 2) void flash_attn_mfma(
    const ushort* __restrict__ qh, const ushort* __restrict__ ql,
    const ushort* __restrict__ kh, const ushort* __restrict__ kl,
    const ushort* __restrict__ vt, float* __restrict__ sa) {
  __shared__ float S[32 * 132];
  __shared__ ushort P[32 * 128];
  __shared__ float mrun[32], lrun[32], facl[32];
  const int tid = threadIdx.x;
  const int w = tid >> 6;
  const int l = tid & 63;
  const int lr = l & 15;   // A-row / B-col / C-col lane index
  const int lg = l >> 4;   // k-group (frag) / row-group (C)
  const int q0 = blockIdx.x * 32;

  // Q fragments (hi+lo, scale pre-folded) held in registers for all 64 tiles.
  bf16x8 qfh[2][4], qfl[2][4];
#pragma unroll
  for (int mt = 0; mt < 2; ++mt)
#pragma unroll
    for (int ks = 0; ks < 4; ++ks) {
      const size_t off = (size_t)(q0 + mt * 16 + lr) * 128 + ks * 32 + lg * 8;
      qfh[mt][ks] = *(const bf16x8*)(qh + off);
      qfl[mt][ks] = *(const bf16x8*)(ql + off);
    }
  if (tid < 32) { mrun[tid] = -INFINITY; lrun[tid] = 0.0f; }

  f32x4 acc[2][8];
#pragma unroll
  for (int mt = 0; mt < 2; ++mt)
#pragma unroll
    for (int nt = 0; nt < 8; ++nt) {
      f32x4 z = {0.0f, 0.0f, 0.0f, 0.0f};
      acc[mt][nt] = z;
    }
  __syncthreads();

  for (int t = 0; t < 64; ++t) {
    const int t0 = t * 128;
    // ---- scores: S[32][w*16+..] = qh kh^T + qh kl^T + ql kh^T ----
    f32x4 sf[2];
    {
      f32x4 z = {0.0f, 0.0f, 0.0f, 0.0f};
      sf[0] = z; sf[1] = z;
    }
#pragma unroll
    for (int ks = 0; ks < 4; ++ks) {
      const size_t ko = (size_t)(t0 + w * 16 + lr) * 128 + ks * 32 + lg * 8;
      const bf16x8 kfh = *(const bf16x8*)(kh + ko);
      const bf16x8 kfl = *(const bf16x8*)(kl + ko);
#pragma unroll
      for (int mt = 0; mt < 2; ++mt) {
        sf[mt] = __builtin_amdgcn_mfma_f32_16x16x32_bf16(qfh[mt][ks], kfh, sf[mt], 0, 0, 0);
        sf[mt] = __builtin_amdgcn_mfma_f32_16x16x32_bf16(qfh[mt][ks], kfl, sf[mt], 0, 0, 0);
        sf[mt] = __builtin_amdgcn_mfma_f32_16x16x32_bf16(qfl[mt][ks], kfh, sf[mt], 0, 0, 0);
      }
    }
#pragma unroll
    for (int mt = 0; mt < 2; ++mt)
#pragma unroll
      for (int r = 0; r < 4; ++r)
        S[(mt * 16 + lg * 4 + r) * 132 + w * 16 + lr] = sf[mt][r];
    __syncthreads();

    // ---- online softmax: wave w owns rows w*4..w*4+3, 2 cols/lane ----
#pragma unroll
    for (int qq = 0; qq < 4; ++qq) {
      const int r = w * 4 + qq;
      const float p0 = S[r * 132 + 2 * l];
      const float p1 = S[r * 132 + 2 * l + 1];
      float mx = fmaxf(p0, p1);
#pragma unroll
      for (int off = 32; off > 0; off >>= 1) mx = fmaxf(mx, __shfl_xor(mx, off));
      const float mo = mrun[r];
      const float mn = fmaxf(mo, mx);
      const float e0 = __expf(p0 - mn);
      const float e1 = __expf(p1 - mn);
      float sm = e0 + e1;
#pragma unroll
      for (int off = 32; off > 0; off >>= 1) sm += __shfl_xor(sm, off);
      const uint pu = ((uint)f2bf(e1) << 16) | f2bf(e0);
      *(uint*)((char*)P + ((r * 256 + l * 4) ^ ((r & 7) << 4))) = pu;
      if (l == 0) {
        const float fac = __expf(mo - mn);
        facl[r] = fac;
        mrun[r] = mn;
        lrun[r] = lrun[r] * fac + sm;
      }
    }
    __syncthreads();

    // ---- rescale accumulators ----
#pragma unroll
    for (int mt = 0; mt < 2; ++mt) {
#pragma unroll
      for (int r = 0; r < 4; ++r) {
        const float f = facl[mt * 16 + lg * 4 + r];
#pragma unroll
        for (int nt = 0; nt < 8; ++nt) acc[mt][nt][r] *= f;
      }
    }
    // ---- load P A-frags from swizzled LDS ----
    bf16x8 pf[2][4];
#pragma unroll
    for (int mt = 0; mt < 2; ++mt)
#pragma unroll
      for (int ks = 0; ks < 4; ++ks) {
        const int row = mt * 16 + lr;
        const int addr = (row * 256 + ks * 64 + lg * 16) ^ ((row & 7) << 4);
        pf[mt][ks] = *(const bf16x8*)((char*)P + addr);
      }
    // ---- PV: acc[mt][nt] += P[.][ks] * vT ----
#pragma unroll
    for (int ks = 0; ks < 4; ++ks) {
#pragma unroll
      for (int nt = 0; nt < 8; ++nt) {
        const bf16x8 vf = *(const bf16x8*)(vt + (size_t)(w * 128 + nt * 16 + lr) * 8192 + t0 + ks * 32 + lg * 8);
        acc[0][nt] = __builtin_amdgcn_mfma_f32_16x16x32_bf16(pf[0][ks], vf, acc[0][nt], 0, 0, 0);
        acc[1][nt] = __builtin_amdgcn_mfma_f32_16x16x32_bf16(pf[1][ks], vf, acc[1][nt], 0, 0, 0);
      }
    }
  }
  // ---- epilogue: divide by softmax denom, write sa ----
#pragma unroll
  for (int mt = 0; mt < 2; ++mt) {
#pragma unroll
    for (int r = 0; r < 4; ++r) {
      const int row = mt * 16 + lg * 4 + r;
      const float inv = 1.0f / lrun[row];
#pragma unroll
      for (int nt = 0; nt < 8; ++nt)
        sa[(size_t)(q0 + row) * 1024 + w * 128 + nt * 16 + lr] = acc[mt][nt][r] * inv;
    }
  }
}

// ---------------------------------------------------------------------------
// out = LayerNorm(a + b) over last dim (1024). Safe with o == b.
// ---------------------------------------------------------------------------
__global__ __launch_bounds__(256) void ln_add(const float* __restrict__ a,
                                              const float* __restrict__ b,
                                              float* __restrict__ o) {
  const int row = blockIdx.x;
  const int tid = threadIdx.x;
  const size_t base = (size_t)row * 256 + tid;
  const float4 av = ((const float4*)a)[base];
  const float4 bv = ((const float4*)b)[base];
  float4 y;
  y.x = av.x + bv.x; y.y = av.y + bv.y;
  y.z = av.z + bv.z; y.w = av.w + bv.w;
  float s1 = y.x + y.y + y.z + y.w;
  float s2 = y.x * y.x + y.y * y.y + y.z * y.z + y.w * y.w;
#pragma unroll
  for (int off = 32; off > 0; off >>= 1) {
    s1 += __shfl_xor(s1, off);
    s2 += __shfl_xor(s2, off);
  }
  __shared__ float r1[4];
  __shared__ float r2[4];
  if ((tid & 63) == 0) { r1[tid >> 6] = s1; r2[tid >> 6] = s2; }
  __syncthreads();
  s1 = r1[0] + r1[1] + r1[2] + r1[3];
  s2 = r2[0] + r2[1] + r2[2] + r2[3];
  const float mu = s1 * (1.0f / 1024.0f);
  const float var = s2 * (1.0f / 1024.0f) - mu * mu;
  const float rs = rsqrtf(var + 1e-5f);
  float4 ov;
  ov.x = (y.x - mu) * rs; ov.y = (y.y - mu) * rs;
  ov.z = (y.z - mu) * rs; ov.w = (y.w - mu) * rs;
  ((float4*)o)[base] = ov;
}

// ---------------------------------------------------------------------------
extern "C" void kernel_launch(void* const* d_in, const int* in_sizes, int n_in,
                              void* d_out, int out_size, void* d_ws, size_t ws_size,
                              hipStream_t stream) {
  const float* x  = (const float*)d_in[0];
  const float* Wq = (const float*)d_in[1];
  const float* Wk = (const float*)d_in[2];
  const float* Wv = (const float*)d_in[3];
  const float* Wl = (const float*)d_in[4];
  float* out = (float*)d_out;

  // ws layout: q(4MB) k(4MB) qh/ql/kh/kl(2MB ea) vT_bf16(16MB) sa(32MB) h(32MB)
  float* ws = (float*)d_ws;
  float*  q  = ws;
  float*  k  = q + (size_t)N_TOK * D_QK;
  ushort* qh = (ushort*)(k + (size_t)N_TOK * D_QK);
  ushort* ql = qh + (size_t)N_TOK * D_QK;
  ushort* kh = ql + (size_t)N_TOK * D_QK;
  ushort* kl = kh + (size_t)N_TOK * D_QK;
  ushort* vt = kl + (size_t)N_TOK * D_QK;
  float*  sa = (float*)(vt + (size_t)D_IN * N_TOK);
  float*  h  = sa + (size_t)N_TOK * D_IN;

  const float scale = 11.31370849898476f;  // sqrt(128)

  gemm_abt<<<dim3(D_QK / 64, N_TOK / 64), 256, 0, stream>>>(x, Wq, q, N_TOK, D_QK, D_IN);
  gemm_abt<<<dim3(D_QK / 64, N_TOK / 64), 256, 0, stream>>>(x, Wk, k, N_TOK, D_QK, D_IN);
  split_hl<<<(N_TOK * D_QK / 4) / 256, 256, 0, stream>>>(q, qh, ql, scale);
  split_hl<<<(N_TOK * D_QK / 4) / 256, 256, 0, stream>>>(k, kh, kl, 1.0f);
  // vT[1024][8192] = Wv x^T, stored bf16
  gemm_abt_bf16<<<dim3(N_TOK / 64, D_IN / 64), 256, 0, stream>>>(Wv, x, vt, D_IN, N_TOK, D_IN);
  flash_attn_mfma<<<N_TOK / 32, 512, 0, stream>>>(qh, ql, kh, kl, vt, sa);
  ln_add<<<N_TOK, 256, 0, stream>>>(x, sa, h);
  gemm_abt<<<dim3(D_IN / 64, N_TOK / 64), 256, 0, stream>>>(h, Wl, out, N_TOK, D_IN, D_IN);
  ln_add<<<N_TOK, 256, 0, stream>>>(sa, out, out);
}

// Round 3
// 741.743 us; speedup vs baseline: 6.9635x; 1.9818x over previous
//
#include <hip/hip_runtime.h>
#include <hip/hip_bf16.h>
#include <math.h>

#define N_TOK 8192
#define D_IN  1024
#define D_QK  128

typedef short bf16x8 __attribute__((ext_vector_type(8)));
typedef float f32x4 __attribute__((ext_vector_type(4)));
typedef unsigned short u16;
typedef u16 u16x8 __attribute__((ext_vector_type(8)));

static __device__ __forceinline__ u16 f2bf(float f) {
  __hip_bfloat16 b = __float2bfloat16(f);
  return *(u16*)&b;
}
static __device__ __forceinline__ float bf2f(u16 u) {
  __hip_bfloat16 b = *(__hip_bfloat16*)&u;
  return __bfloat162float(b);
}

static __device__ __forceinline__ void gload_lds16(const void* g, void* lds) {
  __builtin_amdgcn_global_load_lds(
      (const __attribute__((address_space(1))) unsigned int*)g,
      (__attribute__((address_space(3))) unsigned int*)lds, 16, 0, 0);
}

// ---------------------------------------------------------------------------
// f32 GEMM: C[M][N] = A[M][K] * B[N][K]^T  (used only for q,k: accuracy-critical)
// ---------------------------------------------------------------------------
__global__ __launch_bounds__(256) void gemm_abt(const float* __restrict__ A,
                                                const float* __restrict__ B,
                                                float* __restrict__ C,
                                                int M, int N, int K) {
  __shared__ float As[16][68];
  __shared__ float Bs[16][68];
  const int tid = threadIdx.x;
  const int m0 = blockIdx.y * 64;
  const int n0 = blockIdx.x * 64;
  const int tr = tid >> 4;
  const int tc = tid & 15;
  const int srow = tid >> 2;
  const int sk = tid & 3;
  float acc[4][4] = {};
  for (int kt = 0; kt < K; kt += 16) {
    const float4 a = *(const float4*)&A[(size_t)(m0 + srow) * K + kt + sk * 4];
    const float4 b = *(const float4*)&B[(size_t)(n0 + srow) * K + kt + sk * 4];
    As[sk * 4 + 0][srow] = a.x; As[sk * 4 + 1][srow] = a.y;
    As[sk * 4 + 2][srow] = a.z; As[sk * 4 + 3][srow] = a.w;
    Bs[sk * 4 + 0][srow] = b.x; Bs[sk * 4 + 1][srow] = b.y;
    Bs[sk * 4 + 2][srow] = b.z; Bs[sk * 4 + 3][srow] = b.w;
    __syncthreads();
#pragma unroll
    for (int kk = 0; kk < 16; ++kk) {
      const float4 av = *(const float4*)&As[kk][tr * 4];
      const float4 bv = *(const float4*)&Bs[kk][tc * 4];
      acc[0][0] += av.x * bv.x; acc[0][1] += av.x * bv.y;
      acc[0][2] += av.x * bv.z; acc[0][3] += av.x * bv.w;
      acc[1][0] += av.y * bv.x; acc[1][1] += av.y * bv.y;
      acc[1][2] += av.y * bv.z; acc[1][3] += av.y * bv.w;
      acc[2][0] += av.z * bv.x; acc[2][1] += av.z * bv.y;
      acc[2][2] += av.z * bv.z; acc[2][3] += av.z * bv.w;
      acc[3][0] += av.w * bv.x; acc[3][1] += av.w * bv.y;
      acc[3][2] += av.w * bv.z; acc[3][3] += av.w * bv.w;
    }
    __syncthreads();
  }
#pragma unroll
  for (int i = 0; i < 4; ++i) {
    float4 o;
    o.x = acc[i][0]; o.y = acc[i][1]; o.z = acc[i][2]; o.w = acc[i][3];
    *(float4*)&C[(size_t)(m0 + tr * 4 + i) * N + n0 + tc * 4] = o;
  }
}

// ---------------------------------------------------------------------------
// bf16 MFMA GEMM: C[M][N] = A[M][K] * B[N][K]^T, A/B bf16 row-major.
// 128x128 tile, BK=32, 256 thr / 4 waves (2x2 of 64x64), global_load_lds
// width-16 staging, 2 barriers per K-step (m97 structure).
// F32OUT=1 -> f32 C;  F32OUT=0 -> bf16 C.
// ---------------------------------------------------------------------------
template <int F32OUT>
__global__ __launch_bounds__(256, 2) void gemm_mfma(const u16* __restrict__ A,
                                                    const u16* __restrict__ B,
                                                    void* __restrict__ Cv,
                                                    int M, int N, int K) {
  __shared__ __align__(16) u16 As[128 * 32];
  __shared__ __align__(16) u16 Bs[128 * 32];
  const int tid = threadIdx.x;
  const int w = tid >> 6, l = tid & 63;
  const int lr = l & 15, lg = l >> 4;
  const int m0 = blockIdx.y * 128, n0 = blockIdx.x * 128;
  const int wr = (w >> 1) * 64, wc = (w & 1) * 64;

  f32x4 acc[4][4];
#pragma unroll
  for (int m = 0; m < 4; ++m)
#pragma unroll
    for (int n = 0; n < 4; ++n) {
      f32x4 z = {0.f, 0.f, 0.f, 0.f};
      acc[m][n] = z;
    }

  // staging geometry: instr i of wave w covers LDS bytes [(w*2+i)*1024, +1024),
  // lane l -> row (w*2+i)*16 + (l>>2), col elems (l&3)*8 of the 128x32 tile.
  const int ldsb0 = (w * 2 + 0) * 1024;
  const int ldsb1 = (w * 2 + 1) * 1024;
  const int srow0 = (w * 2 + 0) * 16 + (l >> 2);
  const int srow1 = (w * 2 + 1) * 16 + (l >> 2);
  const int scol = (l & 3) * 8;

  for (int kt = 0; kt < K; kt += 32) {
    gload_lds16(A + (size_t)(m0 + srow0) * K + kt + scol, (char*)As + ldsb0);
    gload_lds16(A + (size_t)(m0 + srow1) * K + kt + scol, (char*)As + ldsb1);
    gload_lds16(B + (size_t)(n0 + srow0) * K + kt + scol, (char*)Bs + ldsb0);
    gload_lds16(B + (size_t)(n0 + srow1) * K + kt + scol, (char*)Bs + ldsb1);
    __syncthreads();
    bf16x8 af[4], bfr[4];
#pragma unroll
    for (int m = 0; m < 4; ++m)
      af[m] = *(const bf16x8*)((char*)As + (wr + m * 16 + lr) * 64 + lg * 16);
#pragma unroll
    for (int n = 0; n < 4; ++n)
      bfr[n] = *(const bf16x8*)((char*)Bs + (wc + n * 16 + lr) * 64 + lg * 16);
#pragma unroll
    for (int m = 0; m < 4; ++m)
#pragma unroll
      for (int n = 0; n < 4; ++n)
        acc[m][n] = __builtin_amdgcn_mfma_f32_16x16x32_bf16(af[m], bfr[n], acc[m][n], 0, 0, 0);
    __syncthreads();
  }
  // epilogue: C layout col=lane&15, row=(lane>>4)*4+reg
#pragma unroll
  for (int m = 0; m < 4; ++m)
#pragma unroll
    for (int n = 0; n < 4; ++n)
#pragma unroll
      for (int r = 0; r < 4; ++r) {
        const size_t row = m0 + wr + m * 16 + lg * 4 + r;
        const size_t col = n0 + wc + n * 16 + lr;
        if (F32OUT)
          ((float*)Cv)[row * N + col] = acc[m][n][r];
        else
          ((u16*)Cv)[row * N + col] = f2bf(acc[m][n][r]);
      }
}

// ---------------------------------------------------------------------------
// elementwise f32 -> bf16 (8 elems/thread)
// ---------------------------------------------------------------------------
__global__ __launch_bounds__(256) void cvt_bf16(const float* __restrict__ in,
                                                u16* __restrict__ out) {
  const size_t idx = (size_t)blockIdx.x * 256 + threadIdx.x;
  const float4 a = ((const float4*)in)[idx * 2];
  const float4 b = ((const float4*)in)[idx * 2 + 1];
  u16x8 o;
  o[0] = f2bf(a.x); o[1] = f2bf(a.y); o[2] = f2bf(a.z); o[3] = f2bf(a.w);
  o[4] = f2bf(b.x); o[5] = f2bf(b.y); o[6] = f2bf(b.z); o[7] = f2bf(b.w);
  ((u16x8*)out)[idx] = o;
}

// ---------------------------------------------------------------------------
// hi/lo bf16 split, row-major out (for Q; scale folded in)
// ---------------------------------------------------------------------------
__global__ __launch_bounds__(256) void split_hl(const float* __restrict__ in,
                                                u16* __restrict__ hi,
                                                u16* __restrict__ lo,
                                                float scale) {
  const int idx = blockIdx.x * 256 + threadIdx.x;
  const float4 v = ((const float4*)in)[idx];
  float f[4] = {v.x * scale, v.y * scale, v.z * scale, v.w * scale};
  u16 h[4], g[4];
#pragma unroll
  for (int i = 0; i < 4; ++i) {
    h[i] = f2bf(f[i]);
    g[i] = f2bf(f[i] - bf2f(h[i]));
  }
  ushort4 hv; hv.x = h[0]; hv.y = h[1]; hv.z = h[2]; hv.w = h[3];
  ushort4 gv; gv.x = g[0]; gv.y = g[1]; gv.z = g[2]; gv.w = g[3];
  ((ushort4*)hi)[idx] = hv;
  ((ushort4*)lo)[idx] = gv;
}

// ---------------------------------------------------------------------------
// hi/lo split of K into MFMA-fragment-tiled layout:
// frag f = (row>>4)*4 + (col>>5); elem (f*512 + l*8 + e) holds
// K[fn*16 + (l&15)][fk*32 + (l>>4)*8 + e].  131072 threads.
// ---------------------------------------------------------------------------
__global__ __launch_bounds__(256) void split_k_t(const float* __restrict__ k,
                                                 u16* __restrict__ khT,
                                                 u16* __restrict__ klT) {
  const int gid = blockIdx.x * 256 + threadIdx.x;
  const int f = gid >> 6, l = gid & 63;
  const int fn = f >> 2, fk = f & 3;
  const int row = fn * 16 + (l & 15);
  const int col = fk * 32 + (l >> 4) * 8;
  const float4 v0 = *(const float4*)&k[(size_t)row * 128 + col];
  const float4 v1 = *(const float4*)&k[(size_t)row * 128 + col + 4];
  const float fv[8] = {v0.x, v0.y, v0.z, v0.w, v1.x, v1.y, v1.z, v1.w};
  u16x8 h, g;
#pragma unroll
  for (int i = 0; i < 8; ++i) {
    h[i] = f2bf(fv[i]);
    g[i] = f2bf(fv[i] - bf2f(h[i]));
  }
  *(u16x8*)(khT + (size_t)f * 512 + l * 8) = h;
  *(u16x8*)(klT + (size_t)f * 512 + l * 8) = g;
}

// ---------------------------------------------------------------------------
// repack vt_rm [1024][8192] bf16 -> fragment-tiled vt_t:
// frag f = (vcol>>4)*256 + (token>>5); elem f*512+l*8+e =
// vt_rm[fn*16 + (l&15)][fk*32 + (l>>4)*8 + e].  1M threads.
// ---------------------------------------------------------------------------
__global__ __launch_bounds__(256) void repack_vt(const u16* __restrict__ vr,
                                                 u16* __restrict__ vt) {
  const int gid = blockIdx.x * 256 + threadIdx.x;
  const int f = gid >> 6, l = gid & 63;
  const int fn = f >> 8, fk = f & 255;
  const size_t src = (size_t)(fn * 16 + (l & 15)) * 8192 + fk * 32 + (l >> 4) * 8;
  const u16x8 v = *(const u16x8*)(vr + src);
  *(u16x8*)(vt + (size_t)f * 512 + l * 8) = v;
}

// ---------------------------------------------------------------------------
// MFMA flash attention. 256 blocks x 512 thr (8 waves), QBLK=32, KVBLK=128.
// K/V fragments loaded coalesced from frag-tiled layouts; K double-buffered
// in registers across tiles; V depth-2 pipelined inside the PV loop.
// ---------------------------------------------------------------------------
__global__ __launch_bounds__(512, 2) void flash_attn_mfma(
    const u16* __restrict__ qh, const u16* __restrict__ ql,
    const u16* __restrict__ khT, const u16* __restrict__ klT,
    const u16* __restrict__ vt, float* __restrict__ sa) {
  __shared__ float S[32 * 132];
  __shared__ __align__(16) u16 P[32 * 128];
  __shared__ float mrun[32], lrun[32], facl[32];
  const int tid = threadIdx.x;
  const int w = tid >> 6, l = tid & 63;
  const int lr = l & 15, lg = l >> 4;
  const int q0 = blockIdx.x * 32;

  // Q fragments (hi+lo) in registers for all 64 tiles.
  bf16x8 qfh[2][4], qfl[2][4];
#pragma unroll
  for (int mt = 0; mt < 2; ++mt)
#pragma unroll
    for (int ks = 0; ks < 4; ++ks) {
      const size_t off = (size_t)(q0 + mt * 16 + lr) * 128 + ks * 32 + lg * 8;
      qfh[mt][ks] = *(const bf16x8*)(qh + off);
      qfl[mt][ks] = *(const bf16x8*)(ql + off);
    }
  if (tid < 32) { mrun[tid] = -INFINITY; lrun[tid] = 0.0f; }

  f32x4 acc[2][8];
#pragma unroll
  for (int mt = 0; mt < 2; ++mt)
#pragma unroll
    for (int nt = 0; nt < 8; ++nt) {
      f32x4 z = {0.f, 0.f, 0.f, 0.f};
      acc[mt][nt] = z;
    }

  // K fragments for tile 0 (coalesced: 1 KB per wave-load).
  bf16x8 kfh[4], kfl[4];
#pragma unroll
  for (int ks = 0; ks < 4; ++ks) {
    kfh[ks] = *(const bf16x8*)(khT + ((size_t)(0 * 8 + w) * 4 + ks) * 512 + l * 8);
    kfl[ks] = *(const bf16x8*)(klT + ((size_t)(0 * 8 + w) * 4 + ks) * 512 + l * 8);
  }
  __syncthreads();

  for (int t = 0; t < 64; ++t) {
    // ---- scores: 3-MFMA hi/lo (f32-accurate logits) ----
    f32x4 sf[2];
    {
      f32x4 z = {0.f, 0.f, 0.f, 0.f};
      sf[0] = z; sf[1] = z;
    }
#pragma unroll
    for (int ks = 0; ks < 4; ++ks)
#pragma unroll
      for (int mt = 0; mt < 2; ++mt) {
        sf[mt] = __builtin_amdgcn_mfma_f32_16x16x32_bf16(qfh[mt][ks], kfh[ks], sf[mt], 0, 0, 0);
        sf[mt] = __builtin_amdgcn_mfma_f32_16x16x32_bf16(qfh[mt][ks], kfl[ks], sf[mt], 0, 0, 0);
        sf[mt] = __builtin_amdgcn_mfma_f32_16x16x32_bf16(qfl[mt][ks], kfh[ks], sf[mt], 0, 0, 0);
      }
#pragma unroll
    for (int mt = 0; mt < 2; ++mt)
#pragma unroll
      for (int r = 0; r < 4; ++r)
        S[(mt * 16 + lg * 4 + r) * 132 + w * 16 + lr] = sf[mt][r];
    __syncthreads();

    // ---- online softmax: wave w owns rows w*4..w*4+3, 2 cols/lane ----
#pragma unroll
    for (int qq = 0; qq < 4; ++qq) {
      const int r = w * 4 + qq;
      const float2 p = *(const float2*)&S[r * 132 + 2 * l];
      float mx = fmaxf(p.x, p.y);
#pragma unroll
      for (int off = 32; off > 0; off >>= 1) mx = fmaxf(mx, __shfl_xor(mx, off));
      const float mo = mrun[r];
      const float mn = fmaxf(mo, mx);
      const float e0 = __expf(p.x - mn);
      const float e1 = __expf(p.y - mn);
      float sm = e0 + e1;
#pragma unroll
      for (int off = 32; off > 0; off >>= 1) sm += __shfl_xor(sm, off);
      const uint pu = ((uint)f2bf(e1) << 16) | f2bf(e0);
      *(uint*)((char*)P + ((r * 256 + l * 4) ^ ((r & 7) << 4)));  // addr compute kept simple below
      *(uint*)((char*)P + ((r * 256 + l * 4) ^ ((r & 7) << 4))) = pu;
      if (l == 0) {
        const float fac = __expf(mo - mn);
        facl[r] = fac;
        mrun[r] = mn;
        lrun[r] = lrun[r] * fac + sm;
      }
    }
    __syncthreads();

    // ---- P A-frags from swizzled LDS ----
    bf16x8 pf[2][4];
#pragma unroll
    for (int mt = 0; mt < 2; ++mt)
#pragma unroll
      for (int ks = 0; ks < 4; ++ks) {
        const int row = mt * 16 + lr;
        const int addr = (row * 256 + ks * 64 + lg * 16) ^ ((row & 7) << 4);
        pf[mt][ks] = *(const bf16x8*)((char*)P + addr);
      }

    // ---- V ks=0 prefetch + K(t+1) prefetch (all coalesced 1 KB loads) ----
    bf16x8 va[8], vb[8];
#pragma unroll
    for (int nt = 0; nt < 8; ++nt)
      va[nt] = *(const bf16x8*)(vt + ((size_t)(w * 8 + nt) * 256 + t * 4 + 0) * 512 + l * 8);
    if (t < 63) {
#pragma unroll
      for (int ks = 0; ks < 4; ++ks) {
        kfh[ks] = *(const bf16x8*)(khT + ((size_t)((t + 1) * 8 + w) * 4 + ks) * 512 + l * 8);
        kfl[ks] = *(const bf16x8*)(klT + ((size_t)((t + 1) * 8 + w) * 4 + ks) * 512 + l * 8);
      }
    }
    // ---- rescale accumulators (hides prefetch latency) ----
#pragma unroll
    for (int mt = 0; mt < 2; ++mt)
#pragma unroll
      for (int r = 0; r < 4; ++r) {
        const float f = facl[mt * 16 + lg * 4 + r];
#pragma unroll
        for (int nt = 0; nt < 8; ++nt) acc[mt][nt][r] *= f;
      }
    // ---- PV: depth-2 pipelined over ks ----
#pragma unroll
    for (int ks = 0; ks < 4; ++ks) {
      if (ks < 3) {
        bf16x8* nxt = (ks & 1) ? va : vb;
#pragma unroll
        for (int nt = 0; nt < 8; ++nt)
          nxt[nt] = *(const bf16x8*)(vt + ((size_t)(w * 8 + nt) * 256 + t * 4 + ks + 1) * 512 + l * 8);
      }
      const bf16x8* cur = (ks & 1) ? vb : va;
#pragma unroll
      for (int nt = 0; nt < 8; ++nt) {
        acc[0][nt] = __builtin_amdgcn_mfma_f32_16x16x32_bf16(pf[0][ks], cur[nt], acc[0][nt], 0, 0, 0);
        acc[1][nt] = __builtin_amdgcn_mfma_f32_16x16x32_bf16(pf[1][ks], cur[nt], acc[1][nt], 0, 0, 0);
      }
    }
  }
  // ---- epilogue ----
#pragma unroll
  for (int mt = 0; mt < 2; ++mt)
#pragma unroll
    for (int r = 0; r < 4; ++r) {
      const int row = mt * 16 + lg * 4 + r;
      const float inv = 1.0f / lrun[row];
#pragma unroll
      for (int nt = 0; nt < 8; ++nt)
        sa[(size_t)(q0 + row) * 1024 + w * 128 + nt * 16 + lr] = acc[mt][nt][r] * inv;
    }
}

// ---------------------------------------------------------------------------
// out(f32) = LayerNorm(a + b) over last dim 1024. Safe with o == b.
// ---------------------------------------------------------------------------
__global__ __launch_bounds__(256) void ln_add(const float* __restrict__ a,
                                              const float* __restrict__ b,
                                              float* __restrict__ o) {
  const int row = blockIdx.x;
  const int tid = threadIdx.x;
  const size_t base = (size_t)row * 256 + tid;
  const float4 av = ((const float4*)a)[base];
  const float4 bv = ((const float4*)b)[base];
  float4 y;
  y.x = av.x + bv.x; y.y = av.y + bv.y;
  y.z = av.z + bv.z; y.w = av.w + bv.w;
  float s1 = y.x + y.y + y.z + y.w;
  float s2 = y.x * y.x + y.y * y.y + y.z * y.z + y.w * y.w;
#pragma unroll
  for (int off = 32; off > 0; off >>= 1) {
    s1 += __shfl_xor(s1, off);
    s2 += __shfl_xor(s2, off);
  }
  __shared__ float r1[4];
  __shared__ float r2[4];
  if ((tid & 63) == 0) { r1[tid >> 6] = s1; r2[tid >> 6] = s2; }
  __syncthreads();
  s1 = r1[0] + r1[1] + r1[2] + r1[3];
  s2 = r2[0] + r2[1] + r2[2] + r2[3];
  const float mu = s1 * (1.0f / 1024.0f);
  const float var = s2 * (1.0f / 1024.0f) - mu * mu;
  const float rs = rsqrtf(var + 1e-5f);
  float4 ov;
  ov.x = (y.x - mu) * rs; ov.y = (y.y - mu) * rs;
  ov.z = (y.z - mu) * rs; ov.w = (y.w - mu) * rs;
  ((float4*)o)[base] = ov;
}

// Same, but bf16 output (h is only consumed as a bf16 GEMM input).
__global__ __launch_bounds__(256) void ln_add_bf16(const float* __restrict__ a,
                                                   const float* __restrict__ b,
                                                   u16* __restrict__ o) {
  const int row = blockIdx.x;
  const int tid = threadIdx.x;
  const size_t base = (size_t)row * 256 + tid;
  const float4 av = ((const float4*)a)[base];
  const float4 bv = ((const float4*)b)[base];
  float4 y;
  y.x = av.x + bv.x; y.y = av.y + bv.y;
  y.z = av.z + bv.z; y.w = av.w + bv.w;
  float s1 = y.x + y.y + y.z + y.w;
  float s2 = y.x * y.x + y.y * y.y + y.z * y.z + y.w * y.w;
#pragma unroll
  for (int off = 32; off > 0; off >>= 1) {
    s1 += __shfl_xor(s1, off);
    s2 += __shfl_xor(s2, off);
  }
  __shared__ float r1[4];
  __shared__ float r2[4];
  if ((tid & 63) == 0) { r1[tid >> 6] = s1; r2[tid >> 6] = s2; }
  __syncthreads();
  s1 = r1[0] + r1[1] + r1[2] + r1[3];
  s2 = r2[0] + r2[1] + r2[2] + r2[3];
  const float mu = s1 * (1.0f / 1024.0f);
  const float var = s2 * (1.0f / 1024.0f) - mu * mu;
  const float rs = rsqrtf(var + 1e-5f);
  ushort4 ov;
  ov.x = f2bf((y.x - mu) * rs); ov.y = f2bf((y.y - mu) * rs);
  ov.z = f2bf((y.z - mu) * rs); ov.w = f2bf((y.w - mu) * rs);
  ((ushort4*)o)[base] = ov;
}

// ---------------------------------------------------------------------------
extern "C" void kernel_launch(void* const* d_in, const int* in_sizes, int n_in,
                              void* d_out, int out_size, void* d_ws, size_t ws_size,
                              hipStream_t stream) {
  const float* x  = (const float*)d_in[0];
  const float* Wq = (const float*)d_in[1];
  const float* Wk = (const float*)d_in[2];
  const float* Wv = (const float*)d_in[3];
  const float* Wl = (const float*)d_in[4];
  float* out = (float*)d_out;

  // workspace layout (byte offsets), total 100 MB
  char* w8 = (char*)d_ws;
  float* q   = (float*)(w8 + (0ull << 20));   // 4 MB
  float* k   = (float*)(w8 + (4ull << 20));   // 4 MB
  u16* qh    = (u16*)(w8 + (8ull << 20));     // 2 MB
  u16* ql    = (u16*)(w8 + (10ull << 20));    // 2 MB
  u16* khT   = (u16*)(w8 + (12ull << 20));    // 2 MB
  u16* klT   = (u16*)(w8 + (14ull << 20));    // 2 MB
  u16* xb    = (u16*)(w8 + (16ull << 20));    // 16 MB
  u16* Wvb   = (u16*)(w8 + (32ull << 20));    // 2 MB
  u16* Wlb   = (u16*)(w8 + (34ull << 20));    // 2 MB
  u16* vtr   = (u16*)(w8 + (36ull << 20));    // 16 MB (vt row-major; reused as hb)
  u16* vtt   = (u16*)(w8 + (52ull << 20));    // 16 MB (vt frag-tiled)
  float* sa  = (float*)(w8 + (68ull << 20));  // 32 MB
  u16* hb    = vtr;                           // alias: vtr dead after repack

  const float scale = 11.31370849898476f;  // sqrt(128)

  // q,k in f32 (logit-critical), then hi/lo split
  gemm_abt<<<dim3(2, 128), 256, 0, stream>>>(x, Wq, q, N_TOK, D_QK, D_IN);
  gemm_abt<<<dim3(2, 128), 256, 0, stream>>>(x, Wk, k, N_TOK, D_QK, D_IN);
  split_hl<<<1024, 256, 0, stream>>>(q, qh, ql, scale);
  split_k_t<<<512, 256, 0, stream>>>(k, khT, klT);
  // bf16 copies of x, Wv, Wl
  cvt_bf16<<<4096, 256, 0, stream>>>(x, xb);
  cvt_bf16<<<512, 256, 0, stream>>>(Wv, Wvb);
  cvt_bf16<<<512, 256, 0, stream>>>(Wl, Wlb);
  // vt_rm[1024][8192] = Wvb xb^T (bf16 MFMA), then repack to frag-tiled
  gemm_mfma<0><<<dim3(64, 8), 256, 0, stream>>>(Wvb, xb, (void*)vtr, D_IN, N_TOK, D_IN);
  repack_vt<<<4096, 256, 0, stream>>>(vtr, vtt);
  // attention
  flash_attn_mfma<<<256, 512, 0, stream>>>(qh, ql, khT, klT, vtt, sa);
  // h = LN(x + sa) stored bf16
  ln_add_bf16<<<N_TOK, 256, 0, stream>>>(x, sa, hb);
  // out = hb Wlb^T (f32), then out = LN(sa + out) in place
  gemm_mfma<1><<<dim3(8, 64), 256, 0, stream>>>(hb, Wlb, (void*)out, N_TOK, D_IN, D_IN);
  ln_add<<<N_TOK, 256, 0, stream>>>(sa, out, out);
}

// Round 4
// 568.305 us; speedup vs baseline: 9.0886x; 1.3052x over previous
//
#include <hip/hip_runtime.h>
#include <hip/hip_bf16.h>
#include <math.h>

#define N_TOK 8192
#define D_IN  1024
#define D_QK  128

typedef short bf16x8 __attribute__((ext_vector_type(8)));
typedef float f32x4 __attribute__((ext_vector_type(4)));
typedef unsigned short u16;
typedef u16 u16x8 __attribute__((ext_vector_type(8)));

static __device__ __forceinline__ u16 f2bf(float f) {
  __hip_bfloat16 b = __float2bfloat16(f);
  return *(u16*)&b;
}
static __device__ __forceinline__ float bf2f(u16 u) {
  __hip_bfloat16 b = *(__hip_bfloat16*)&u;
  return __bfloat162float(b);
}

static __device__ __forceinline__ void gload_lds16(const void* g, void* lds) {
  __builtin_amdgcn_global_load_lds(
      (const __attribute__((address_space(1))) unsigned int*)g,
      (__attribute__((address_space(3))) unsigned int*)lds, 16, 0, 0);
}

// ---------------------------------------------------------------------------
// bf16 MFMA GEMM: C[M][N] = A[M][K] * B[N][K]^T, 128x128 tile, BK=32,
// 4 waves, global_load_lds staging (m97 structure).
// ---------------------------------------------------------------------------
template <int F32OUT>
__global__ __launch_bounds__(256, 2) void gemm_mfma(const u16* __restrict__ A,
                                                    const u16* __restrict__ B,
                                                    void* __restrict__ Cv,
                                                    int M, int N, int K) {
  __shared__ __align__(16) u16 As[128 * 32];
  __shared__ __align__(16) u16 Bs[128 * 32];
  const int tid = threadIdx.x;
  const int w = tid >> 6, l = tid & 63;
  const int lr = l & 15, lg = l >> 4;
  const int m0 = blockIdx.y * 128, n0 = blockIdx.x * 128;
  const int wr = (w >> 1) * 64, wc = (w & 1) * 64;

  f32x4 acc[4][4];
#pragma unroll
  for (int m = 0; m < 4; ++m)
#pragma unroll
    for (int n = 0; n < 4; ++n) {
      f32x4 z = {0.f, 0.f, 0.f, 0.f};
      acc[m][n] = z;
    }

  const int ldsb0 = (w * 2 + 0) * 1024;
  const int ldsb1 = (w * 2 + 1) * 1024;
  const int srow0 = (w * 2 + 0) * 16 + (l >> 2);
  const int srow1 = (w * 2 + 1) * 16 + (l >> 2);
  const int scol = (l & 3) * 8;

  for (int kt = 0; kt < K; kt += 32) {
    gload_lds16(A + (size_t)(m0 + srow0) * K + kt + scol, (char*)As + ldsb0);
    gload_lds16(A + (size_t)(m0 + srow1) * K + kt + scol, (char*)As + ldsb1);
    gload_lds16(B + (size_t)(n0 + srow0) * K + kt + scol, (char*)Bs + ldsb0);
    gload_lds16(B + (size_t)(n0 + srow1) * K + kt + scol, (char*)Bs + ldsb1);
    __syncthreads();
    bf16x8 af[4], bfr[4];
#pragma unroll
    for (int m = 0; m < 4; ++m)
      af[m] = *(const bf16x8*)((char*)As + (wr + m * 16 + lr) * 64 + lg * 16);
#pragma unroll
    for (int n = 0; n < 4; ++n)
      bfr[n] = *(const bf16x8*)((char*)Bs + (wc + n * 16 + lr) * 64 + lg * 16);
#pragma unroll
    for (int m = 0; m < 4; ++m)
#pragma unroll
      for (int n = 0; n < 4; ++n)
        acc[m][n] = __builtin_amdgcn_mfma_f32_16x16x32_bf16(af[m], bfr[n], acc[m][n], 0, 0, 0);
    __syncthreads();
  }
#pragma unroll
  for (int m = 0; m < 4; ++m)
#pragma unroll
    for (int n = 0; n < 4; ++n)
#pragma unroll
      for (int r = 0; r < 4; ++r) {
        const size_t row = m0 + wr + m * 16 + lg * 4 + r;
        const size_t col = n0 + wc + n * 16 + lr;
        if (F32OUT)
          ((float*)Cv)[row * N + col] = acc[m][n][r];
        else
          ((u16*)Cv)[row * N + col] = f2bf(acc[m][n][r]);
      }
}

// ---------------------------------------------------------------------------
// hi/lo 3-term MFMA GEMM for q,k (f32-equivalent accuracy):
// C = (Ah+Al)(Bh+Bl)^T*scale via AhBh + AhBl + AlBh.
// M-tile 64, N=128 fixed, BK=32, 4 waves. blockIdx.x: 0=Q set, 1=K set.
// Epilogue: hi/lo split of the f32 result, row-major.
// ---------------------------------------------------------------------------
__global__ __launch_bounds__(256, 2) void gemm_hilo(
    const u16* __restrict__ Ah, const u16* __restrict__ Al,
    const u16* __restrict__ BhQ, const u16* __restrict__ BlQ,
    u16* __restrict__ ChQ, u16* __restrict__ ClQ,
    const u16* __restrict__ BhK, const u16* __restrict__ BlK,
    u16* __restrict__ ChK, u16* __restrict__ ClK, int K) {
  const bool isQ = (blockIdx.x == 0);
  const u16* Bh = isQ ? BhQ : BhK;
  const u16* Bl = isQ ? BlQ : BlK;
  u16* Ch = isQ ? ChQ : ChK;
  u16* Cl = isQ ? ClQ : ClK;
  const float scale = isQ ? 11.31370849898476f : 1.0f;
  __shared__ __align__(16) u16 Ahs[64 * 32], Als[64 * 32];
  __shared__ __align__(16) u16 Bhs[128 * 32], Bls[128 * 32];
  const int tid = threadIdx.x;
  const int w = tid >> 6, l = tid & 63;
  const int lr = l & 15, lg = l >> 4;
  const int m0 = blockIdx.y * 64;
  const int wc = w * 32;

  f32x4 acc[4][2];
#pragma unroll
  for (int m = 0; m < 4; ++m)
#pragma unroll
    for (int n = 0; n < 2; ++n) {
      f32x4 z = {0.f, 0.f, 0.f, 0.f};
      acc[m][n] = z;
    }

  const int arow = w * 16 + (l >> 2);
  const int brow0 = (w * 2 + 0) * 16 + (l >> 2);
  const int brow1 = (w * 2 + 1) * 16 + (l >> 2);
  const int scol = (l & 3) * 8;

  for (int kt = 0; kt < K; kt += 32) {
    gload_lds16(Ah + (size_t)(m0 + arow) * K + kt + scol, (char*)Ahs + w * 1024);
    gload_lds16(Al + (size_t)(m0 + arow) * K + kt + scol, (char*)Als + w * 1024);
    gload_lds16(Bh + (size_t)brow0 * K + kt + scol, (char*)Bhs + (w * 2 + 0) * 1024);
    gload_lds16(Bh + (size_t)brow1 * K + kt + scol, (char*)Bhs + (w * 2 + 1) * 1024);
    gload_lds16(Bl + (size_t)brow0 * K + kt + scol, (char*)Bls + (w * 2 + 0) * 1024);
    gload_lds16(Bl + (size_t)brow1 * K + kt + scol, (char*)Bls + (w * 2 + 1) * 1024);
    __syncthreads();
    bf16x8 afh[4], afl[4], bfh[2], bfl[2];
#pragma unroll
    for (int m = 0; m < 4; ++m) {
      afh[m] = *(const bf16x8*)((char*)Ahs + (m * 16 + lr) * 64 + lg * 16);
      afl[m] = *(const bf16x8*)((char*)Als + (m * 16 + lr) * 64 + lg * 16);
    }
#pragma unroll
    for (int n = 0; n < 2; ++n) {
      bfh[n] = *(const bf16x8*)((char*)Bhs + (wc + n * 16 + lr) * 64 + lg * 16);
      bfl[n] = *(const bf16x8*)((char*)Bls + (wc + n * 16 + lr) * 64 + lg * 16);
    }
#pragma unroll
    for (int m = 0; m < 4; ++m)
#pragma unroll
      for (int n = 0; n < 2; ++n) {
        acc[m][n] = __builtin_amdgcn_mfma_f32_16x16x32_bf16(afh[m], bfh[n], acc[m][n], 0, 0, 0);
        acc[m][n] = __builtin_amdgcn_mfma_f32_16x16x32_bf16(afh[m], bfl[n], acc[m][n], 0, 0, 0);
        acc[m][n] = __builtin_amdgcn_mfma_f32_16x16x32_bf16(afl[m], bfh[n], acc[m][n], 0, 0, 0);
      }
    __syncthreads();
  }
#pragma unroll
  for (int m = 0; m < 4; ++m)
#pragma unroll
    for (int n = 0; n < 2; ++n)
#pragma unroll
      for (int r = 0; r < 4; ++r) {
        const size_t row = m0 + m * 16 + lg * 4 + r;
        const size_t col = wc + n * 16 + lr;
        const float v = acc[m][n][r] * scale;
        const u16 h = f2bf(v);
        Ch[row * 128 + col] = h;
        Cl[row * 128 + col] = f2bf(v - bf2f(h));
      }
}

// ---------------------------------------------------------------------------
__global__ __launch_bounds__(256) void cvt_bf16(const float* __restrict__ in,
                                                u16* __restrict__ out) {
  const size_t idx = (size_t)blockIdx.x * 256 + threadIdx.x;
  const float4 a = ((const float4*)in)[idx * 2];
  const float4 b = ((const float4*)in)[idx * 2 + 1];
  u16x8 o;
  o[0] = f2bf(a.x); o[1] = f2bf(a.y); o[2] = f2bf(a.z); o[3] = f2bf(a.w);
  o[4] = f2bf(b.x); o[5] = f2bf(b.y); o[6] = f2bf(b.z); o[7] = f2bf(b.w);
  ((u16x8*)out)[idx] = o;
}

// hi/lo bf16 split of an f32 array (row-major preserved)
__global__ __launch_bounds__(256) void split_hl(const float* __restrict__ in,
                                                u16* __restrict__ hi,
                                                u16* __restrict__ lo) {
  const size_t idx = (size_t)blockIdx.x * 256 + threadIdx.x;
  const float4 v = ((const float4*)in)[idx];
  float f[4] = {v.x, v.y, v.z, v.w};
  u16 h[4], g[4];
#pragma unroll
  for (int i = 0; i < 4; ++i) {
    h[i] = f2bf(f[i]);
    g[i] = f2bf(f[i] - bf2f(h[i]));
  }
  ushort4 hv; hv.x = h[0]; hv.y = h[1]; hv.z = h[2]; hv.w = h[3];
  ushort4 gv; gv.x = g[0]; gv.y = g[1]; gv.z = g[2]; gv.w = g[3];
  ((ushort4*)hi)[idx] = hv;
  ((ushort4*)lo)[idx] = gv;
}

// ---------------------------------------------------------------------------
// repack k hi/lo row-major [8192][128] bf16 -> MFMA-fragment-tiled:
// frag f = (tok>>4)*4 + (col>>5); elem f*512+l*8+e = K[fn*16+(l&15)][fk*32+(l>>4)*8+e]
// ---------------------------------------------------------------------------
__global__ __launch_bounds__(256) void repack_k(const u16* __restrict__ krh,
                                                const u16* __restrict__ krl,
                                                u16* __restrict__ khT,
                                                u16* __restrict__ klT) {
  const int gid = blockIdx.x * 256 + threadIdx.x;
  const int f = gid >> 6, l = gid & 63;
  const int fn = f >> 2, fk = f & 3;
  const size_t src = (size_t)(fn * 16 + (l & 15)) * 128 + fk * 32 + (l >> 4) * 8;
  *(u16x8*)(khT + (size_t)f * 512 + l * 8) = *(const u16x8*)(krh + src);
  *(u16x8*)(klT + (size_t)f * 512 + l * 8) = *(const u16x8*)(krl + src);
}

// repack vt row-major [1024][8192] bf16 -> fragment-tiled
__global__ __launch_bounds__(256) void repack_vt(const u16* __restrict__ vr,
                                                 u16* __restrict__ vt) {
  const int gid = blockIdx.x * 256 + threadIdx.x;
  const int f = gid >> 6, l = gid & 63;
  const int fn = f >> 8, fk = f & 255;
  const size_t src = (size_t)(fn * 16 + (l & 15)) * 8192 + fk * 32 + (l >> 4) * 8;
  *(u16x8*)(vt + (size_t)f * 512 + l * 8) = *(const u16x8*)(vr + src);
}

// ---------------------------------------------------------------------------
// MFMA flash attention. 256 blocks x 8 waves, QBLK=32, KVBLK=128.
// Q hi/lo in XOR-swizzled LDS; K in regs (prefetched 1 tile ahead);
// V chunks ks0-2 issued before scores (hidden under scores+softmax), ks3
// reuses buffer A after ks0's MFMAs. setprio around MFMA clusters.
// ---------------------------------------------------------------------------
#define PV_STEP(KS, CUR)                                                           \
  {                                                                                \
    const bf16x8 pf0 = *(const bf16x8*)((char*)P +                                 \
        ((lr * 256 + (KS)*64 + lg * 16) ^ ((lr & 7) << 4)));                       \
    const bf16x8 pf1 = *(const bf16x8*)((char*)P +                                 \
        (((16 + lr) * 256 + (KS)*64 + lg * 16) ^ ((lr & 7) << 4)));                \
    __builtin_amdgcn_s_setprio(1);                                                 \
    _Pragma("unroll") for (int nt = 0; nt < 8; ++nt) {                             \
      acc[0][nt] = __builtin_amdgcn_mfma_f32_16x16x32_bf16(pf0, CUR[nt],           \
                                                           acc[0][nt], 0, 0, 0);   \
      acc[1][nt] = __builtin_amdgcn_mfma_f32_16x16x32_bf16(pf1, CUR[nt],           \
                                                           acc[1][nt], 0, 0, 0);   \
    }                                                                              \
    __builtin_amdgcn_s_setprio(0);                                                 \
  }

__global__ __launch_bounds__(512, 1) void flash_attn_mfma(
    const u16* __restrict__ qh, const u16* __restrict__ ql,
    const u16* __restrict__ khT, const u16* __restrict__ klT,
    const u16* __restrict__ vt, float* __restrict__ sa) {
  __shared__ __align__(16) u16 Qs[2 * 4096];  // hi|lo, 32x128 swizzled
  __shared__ float S[32 * 132];
  __shared__ __align__(16) u16 P[32 * 128];
  __shared__ float mrun[32], lrun[32], facl[32];
  const int tid = threadIdx.x;
  const int w = tid >> 6, l = tid & 63;
  const int lr = l & 15, lg = l >> 4;
  const int q0 = blockIdx.x * 32;

  {  // stage Q hi/lo into swizzled LDS (coalesced 16B/lane)
    const int row = tid >> 4, c16 = tid & 15;
    const u16x8 hv = *(const u16x8*)(qh + (size_t)(q0 + row) * 128 + c16 * 8);
    const u16x8 lv = *(const u16x8*)(ql + (size_t)(q0 + row) * 128 + c16 * 8);
    const int b = (row * 256 + c16 * 16) ^ ((row & 7) << 4);
    *(u16x8*)((char*)Qs + b) = hv;
    *(u16x8*)((char*)Qs + 8192 + b) = lv;
  }
  if (tid < 32) { mrun[tid] = -INFINITY; lrun[tid] = 0.f; }

  f32x4 acc[2][8];
#pragma unroll
  for (int mt = 0; mt < 2; ++mt)
#pragma unroll
    for (int nt = 0; nt < 8; ++nt) {
      f32x4 z = {0.f, 0.f, 0.f, 0.f};
      acc[mt][nt] = z;
    }

  bf16x8 kfh[4], kfl[4];
#pragma unroll
  for (int ks = 0; ks < 4; ++ks) {
    kfh[ks] = *(const bf16x8*)(khT + ((size_t)w * 4 + ks) * 512 + l * 8);
    kfl[ks] = *(const bf16x8*)(klT + ((size_t)w * 4 + ks) * 512 + l * 8);
  }
  __syncthreads();

  for (int t = 0; t < 64; ++t) {
    const int c = t * 4;
    // ---- issue V chunks ks0..ks2 (land during scores+softmax) ----
    bf16x8 vA[8], vB[8], vC[8];
#pragma unroll
    for (int nt = 0; nt < 8; ++nt) {
      vA[nt] = *(const bf16x8*)(vt + ((size_t)(w * 8 + nt) * 256 + c + 0) * 512 + l * 8);
      vB[nt] = *(const bf16x8*)(vt + ((size_t)(w * 8 + nt) * 256 + c + 1) * 512 + l * 8);
      vC[nt] = *(const bf16x8*)(vt + ((size_t)(w * 8 + nt) * 256 + c + 2) * 512 + l * 8);
    }
    // ---- scores (Q from swizzled LDS, K from regs) ----
    f32x4 sf0 = {0.f, 0.f, 0.f, 0.f}, sf1 = {0.f, 0.f, 0.f, 0.f};
    __builtin_amdgcn_s_setprio(1);
#pragma unroll
    for (int ks = 0; ks < 4; ++ks) {
      const int b0 = (lr * 256 + ks * 64 + lg * 16) ^ ((lr & 7) << 4);
      const int b1 = ((16 + lr) * 256 + ks * 64 + lg * 16) ^ ((lr & 7) << 4);
      const bf16x8 qh0 = *(const bf16x8*)((char*)Qs + b0);
      const bf16x8 qh1 = *(const bf16x8*)((char*)Qs + b1);
      const bf16x8 ql0 = *(const bf16x8*)((char*)Qs + 8192 + b0);
      const bf16x8 ql1 = *(const bf16x8*)((char*)Qs + 8192 + b1);
      sf0 = __builtin_amdgcn_mfma_f32_16x16x32_bf16(qh0, kfh[ks], sf0, 0, 0, 0);
      sf0 = __builtin_amdgcn_mfma_f32_16x16x32_bf16(qh0, kfl[ks], sf0, 0, 0, 0);
      sf0 = __builtin_amdgcn_mfma_f32_16x16x32_bf16(ql0, kfh[ks], sf0, 0, 0, 0);
      sf1 = __builtin_amdgcn_mfma_f32_16x16x32_bf16(qh1, kfh[ks], sf1, 0, 0, 0);
      sf1 = __builtin_amdgcn_mfma_f32_16x16x32_bf16(qh1, kfl[ks], sf1, 0, 0, 0);
      sf1 = __builtin_amdgcn_mfma_f32_16x16x32_bf16(ql1, kfh[ks], sf1, 0, 0, 0);
    }
    __builtin_amdgcn_s_setprio(0);
#pragma unroll
    for (int r = 0; r < 4; ++r) {
      S[(lg * 4 + r) * 132 + w * 16 + lr] = sf0[r];
      S[(16 + lg * 4 + r) * 132 + w * 16 + lr] = sf1[r];
    }
    __syncthreads();

    // ---- online softmax, 4 rows batched for ILP ----
    float p0[4], p1[4], mx[4];
#pragma unroll
    for (int qq = 0; qq < 4; ++qq) {
      const float2 p = *(const float2*)&S[(w * 4 + qq) * 132 + 2 * l];
      p0[qq] = p.x; p1[qq] = p.y;
      mx[qq] = fmaxf(p.x, p.y);
    }
#pragma unroll
    for (int off = 32; off; off >>= 1)
#pragma unroll
      for (int qq = 0; qq < 4; ++qq) mx[qq] = fmaxf(mx[qq], __shfl_xor(mx[qq], off));
    float mo[4], mn[4], sm[4], e0[4], e1[4];
#pragma unroll
    for (int qq = 0; qq < 4; ++qq) {
      mo[qq] = mrun[w * 4 + qq];
      mn[qq] = fmaxf(mo[qq], mx[qq]);
      e0[qq] = __expf(p0[qq] - mn[qq]);
      e1[qq] = __expf(p1[qq] - mn[qq]);
      sm[qq] = e0[qq] + e1[qq];
    }
#pragma unroll
    for (int off = 32; off; off >>= 1)
#pragma unroll
      for (int qq = 0; qq < 4; ++qq) sm[qq] += __shfl_xor(sm[qq], off);
#pragma unroll
    for (int qq = 0; qq < 4; ++qq) {
      const int r = w * 4 + qq;
      const uint pu = ((uint)f2bf(e1[qq]) << 16) | f2bf(e0[qq]);
      *(uint*)((char*)P + ((r * 256 + l * 4) ^ ((r & 7) << 4))) = pu;
      if (l == 0) {
        const float fac = __expf(mo[qq] - mn[qq]);
        facl[r] = fac;
        mrun[r] = mn[qq];
        lrun[r] = lrun[r] * fac + sm[qq];
      }
    }
    __syncthreads();

    // ---- K(t+1) prefetch (consumed next tile's scores) ----
    if (t < 63) {
#pragma unroll
      for (int ks = 0; ks < 4; ++ks) {
        kfh[ks] = *(const bf16x8*)(khT + ((size_t)((t + 1) * 8 + w) * 4 + ks) * 512 + l * 8);
        kfl[ks] = *(const bf16x8*)(klT + ((size_t)((t + 1) * 8 + w) * 4 + ks) * 512 + l * 8);
      }
    }
    // ---- rescale (skipped when factor == 1) ----
#pragma unroll
    for (int mt = 0; mt < 2; ++mt)
#pragma unroll
      for (int r = 0; r < 4; ++r) {
        const float f = facl[mt * 16 + lg * 4 + r];
        if (f != 1.0f) {
#pragma unroll
          for (int nt = 0; nt < 8; ++nt) acc[mt][nt][r] *= f;
        }
      }
    // ---- PV ----
    PV_STEP(0, vA)
#pragma unroll
    for (int nt = 0; nt < 8; ++nt)  // reuse vA for ks3 (window: ks1+ks2 MFMAs)
      vA[nt] = *(const bf16x8*)(vt + ((size_t)(w * 8 + nt) * 256 + c + 3) * 512 + l * 8);
    PV_STEP(1, vB)
    PV_STEP(2, vC)
    PV_STEP(3, vA)
  }
  // ---- epilogue ----
#pragma unroll
  for (int mt = 0; mt < 2; ++mt)
#pragma unroll
    for (int r = 0; r < 4; ++r) {
      const int row = mt * 16 + lg * 4 + r;
      const float inv = 1.0f / lrun[row];
#pragma unroll
      for (int nt = 0; nt < 8; ++nt)
        sa[(size_t)(q0 + row) * 1024 + w * 128 + nt * 16 + lr] = acc[mt][nt][r] * inv;
    }
}

// ---------------------------------------------------------------------------
// out(f32) = LayerNorm(a + b) over last dim 1024. Safe with o == b.
// ---------------------------------------------------------------------------
__global__ __launch_bounds__(256) void ln_add(const float* __restrict__ a,
                                              const float* __restrict__ b,
                                              float* __restrict__ o) {
  const int row = blockIdx.x;
  const int tid = threadIdx.x;
  const size_t base = (size_t)row * 256 + tid;
  const float4 av = ((const float4*)a)[base];
  const float4 bv = ((const float4*)b)[base];
  float4 y;
  y.x = av.x + bv.x; y.y = av.y + bv.y;
  y.z = av.z + bv.z; y.w = av.w + bv.w;
  float s1 = y.x + y.y + y.z + y.w;
  float s2 = y.x * y.x + y.y * y.y + y.z * y.z + y.w * y.w;
#pragma unroll
  for (int off = 32; off > 0; off >>= 1) {
    s1 += __shfl_xor(s1, off);
    s2 += __shfl_xor(s2, off);
  }
  __shared__ float r1[4];
  __shared__ float r2[4];
  if ((tid & 63) == 0) { r1[tid >> 6] = s1; r2[tid >> 6] = s2; }
  __syncthreads();
  s1 = r1[0] + r1[1] + r1[2] + r1[3];
  s2 = r2[0] + r2[1] + r2[2] + r2[3];
  const float mu = s1 * (1.0f / 1024.0f);
  const float var = s2 * (1.0f / 1024.0f) - mu * mu;
  const float rs = rsqrtf(var + 1e-5f);
  float4 ov;
  ov.x = (y.x - mu) * rs; ov.y = (y.y - mu) * rs;
  ov.z = (y.z - mu) * rs; ov.w = (y.w - mu) * rs;
  ((float4*)o)[base] = ov;
}

__global__ __launch_bounds__(256) void ln_add_bf16(const float* __restrict__ a,
                                                   const float* __restrict__ b,
                                                   u16* __restrict__ o) {
  const int row = blockIdx.x;
  const int tid = threadIdx.x;
  const size_t base = (size_t)row * 256 + tid;
  const float4 av = ((const float4*)a)[base];
  const float4 bv = ((const float4*)b)[base];
  float4 y;
  y.x = av.x + bv.x; y.y = av.y + bv.y;
  y.z = av.z + bv.z; y.w = av.w + bv.w;
  float s1 = y.x + y.y + y.z + y.w;
  float s2 = y.x * y.x + y.y * y.y + y.z * y.z + y.w * y.w;
#pragma unroll
  for (int off = 32; off > 0; off >>= 1) {
    s1 += __shfl_xor(s1, off);
    s2 += __shfl_xor(s2, off);
  }
  __shared__ float r1[4];
  __shared__ float r2[4];
  if ((tid & 63) == 0) { r1[tid >> 6] = s1; r2[tid >> 6] = s2; }
  __syncthreads();
  s1 = r1[0] + r1[1] + r1[2] + r1[3];
  s2 = r2[0] + r2[1] + r2[2] + r2[3];
  const float mu = s1 * (1.0f / 1024.0f);
  const float var = s2 * (1.0f / 1024.0f) - mu * mu;
  const float rs = rsqrtf(var + 1e-5f);
  ushort4 ov;
  ov.x = f2bf((y.x - mu) * rs); ov.y = f2bf((y.y - mu) * rs);
  ov.z = f2bf((y.z - mu) * rs); ov.w = f2bf((y.w - mu) * rs);
  ((ushort4*)o)[base] = ov;
}

// ---------------------------------------------------------------------------
extern "C" void kernel_launch(void* const* d_in, const int* in_sizes, int n_in,
                              void* d_out, int out_size, void* d_ws, size_t ws_size,
                              hipStream_t stream) {
  const float* x  = (const float*)d_in[0];
  const float* Wq = (const float*)d_in[1];
  const float* Wk = (const float*)d_in[2];
  const float* Wv = (const float*)d_in[3];
  const float* Wl = (const float*)d_in[4];
  float* out = (float*)d_out;

  // workspace (100 MB total), with lifetime-based aliasing:
  //  0- 16: xh
  // 16- 32: xl          -> khT@16, klT@18 after gemm_hilo
  // 32- 48: vtr         -> qh@32 ql@34 krh@36 krl@38 after repack_vt -> hb@32 after flash
  // 48- 64: vtt
  // 64- 96: sa          (wq/wk splits live at 92-93 until flash overwrites)
  // 96-100: Wvb, Wlb
  char* w8 = (char*)d_ws;
  u16* xh  = (u16*)(w8 + (0ull << 20));
  u16* xl  = (u16*)(w8 + (16ull << 20));
  u16* khT = (u16*)(w8 + (16ull << 20));
  u16* klT = (u16*)(w8 + (18ull << 20));
  u16* vtr = (u16*)(w8 + (32ull << 20));
  u16* qh  = (u16*)(w8 + (32ull << 20));
  u16* ql  = (u16*)(w8 + (34ull << 20));
  u16* krh = (u16*)(w8 + (36ull << 20));
  u16* krl = (u16*)(w8 + (38ull << 20));
  u16* hb  = (u16*)(w8 + (32ull << 20));
  u16* vtt = (u16*)(w8 + (48ull << 20));
  float* sa = (float*)(w8 + (64ull << 20));
  u16* wqh = (u16*)(w8 + (92ull << 20));
  u16* wql = (u16*)(w8 + (92ull << 20) + (256ull << 10));
  u16* wkh = (u16*)(w8 + (92ull << 20) + (512ull << 10));
  u16* wkl = (u16*)(w8 + (92ull << 20) + (768ull << 10));
  u16* Wvb = (u16*)(w8 + (96ull << 20));
  u16* Wlb = (u16*)(w8 + (98ull << 20));

  // x -> hi/lo split (hi doubles as the bf16 x for the v-GEMM)
  split_hl<<<8192, 256, 0, stream>>>(x, xh, xl);
  cvt_bf16<<<512, 256, 0, stream>>>(Wv, Wvb);
  cvt_bf16<<<512, 256, 0, stream>>>(Wl, Wlb);
  // vT row-major [1024][8192] = Wvb * xh^T, then frag-tiled repack
  gemm_mfma<0><<<dim3(64, 8), 256, 0, stream>>>(Wvb, xh, (void*)vtr, D_IN, N_TOK, D_IN);
  repack_vt<<<4096, 256, 0, stream>>>(vtr, vtt);
  // weight splits, then q & k in one hi/lo MFMA launch
  split_hl<<<128, 256, 0, stream>>>(Wq, wqh, wql);
  split_hl<<<128, 256, 0, stream>>>(Wk, wkh, wkl);
  gemm_hilo<<<dim3(2, 128), 256, 0, stream>>>(xh, xl, wqh, wql, qh, ql,
                                              wkh, wkl, krh, krl, D_IN);
  repack_k<<<512, 256, 0, stream>>>(krh, krl, khT, klT);
  // attention
  flash_attn_mfma<<<256, 512, 0, stream>>>(qh, ql, khT, klT, vtt, sa);
  // h = LN(x + sa) in bf16
  ln_add_bf16<<<N_TOK, 256, 0, stream>>>(x, sa, hb);
  // out = hb * Wlb^T, then out = LN(sa + out) in place
  gemm_mfma<1><<<dim3(8, 64), 256, 0, stream>>>(hb, Wlb, (void*)out, N_TOK, D_IN, D_IN);
  ln_add<<<N_TOK, 256, 0, stream>>>(sa, out, out);
}

// Round 5
// 550.267 us; speedup vs baseline: 9.3865x; 1.0328x over previous
//
#include <hip/hip_runtime.h>
#include <hip/hip_bf16.h>
#include <math.h>

#define N_TOK 8192
#define D_IN  1024
#define D_QK  128

typedef short bf16x8 __attribute__((ext_vector_type(8)));
typedef float f32x4 __attribute__((ext_vector_type(4)));
typedef unsigned short u16;
typedef u16 u16x8 __attribute__((ext_vector_type(8)));

static __device__ __forceinline__ u16 f2bf(float f) {
  __hip_bfloat16 b = __float2bfloat16(f);
  return *(u16*)&b;
}
static __device__ __forceinline__ float bf2f(u16 u) {
  __hip_bfloat16 b = *(__hip_bfloat16*)&u;
  return __bfloat162float(b);
}

static __device__ __forceinline__ void gload_lds16(const void* g, void* lds) {
  __builtin_amdgcn_global_load_lds(
      (const __attribute__((address_space(1))) unsigned int*)g,
      (__attribute__((address_space(3))) unsigned int*)lds, 16, 0, 0);
}

// ---------------------------------------------------------------------------
// bf16 MFMA GEMM: C[M][N] = A[M][K] * B[N][K]^T, 128x128 tile, BK=32.
// ---------------------------------------------------------------------------
template <int F32OUT>
__global__ __launch_bounds__(256, 2) void gemm_mfma(const u16* __restrict__ A,
                                                    const u16* __restrict__ B,
                                                    void* __restrict__ Cv,
                                                    int M, int N, int K) {
  __shared__ __align__(16) u16 As[128 * 32];
  __shared__ __align__(16) u16 Bs[128 * 32];
  const int tid = threadIdx.x;
  const int w = tid >> 6, l = tid & 63;
  const int lr = l & 15, lg = l >> 4;
  const int m0 = blockIdx.y * 128, n0 = blockIdx.x * 128;
  const int wr = (w >> 1) * 64, wc = (w & 1) * 64;

  f32x4 acc[4][4];
#pragma unroll
  for (int m = 0; m < 4; ++m)
#pragma unroll
    for (int n = 0; n < 4; ++n) {
      f32x4 z = {0.f, 0.f, 0.f, 0.f};
      acc[m][n] = z;
    }

  const int ldsb0 = (w * 2 + 0) * 1024;
  const int ldsb1 = (w * 2 + 1) * 1024;
  const int srow0 = (w * 2 + 0) * 16 + (l >> 2);
  const int srow1 = (w * 2 + 1) * 16 + (l >> 2);
  const int scol = (l & 3) * 8;

  for (int kt = 0; kt < K; kt += 32) {
    gload_lds16(A + (size_t)(m0 + srow0) * K + kt + scol, (char*)As + ldsb0);
    gload_lds16(A + (size_t)(m0 + srow1) * K + kt + scol, (char*)As + ldsb1);
    gload_lds16(B + (size_t)(n0 + srow0) * K + kt + scol, (char*)Bs + ldsb0);
    gload_lds16(B + (size_t)(n0 + srow1) * K + kt + scol, (char*)Bs + ldsb1);
    __syncthreads();
    bf16x8 af[4], bfr[4];
#pragma unroll
    for (int m = 0; m < 4; ++m)
      af[m] = *(const bf16x8*)((char*)As + (wr + m * 16 + lr) * 64 + lg * 16);
#pragma unroll
    for (int n = 0; n < 4; ++n)
      bfr[n] = *(const bf16x8*)((char*)Bs + (wc + n * 16 + lr) * 64 + lg * 16);
#pragma unroll
    for (int m = 0; m < 4; ++m)
#pragma unroll
      for (int n = 0; n < 4; ++n)
        acc[m][n] = __builtin_amdgcn_mfma_f32_16x16x32_bf16(af[m], bfr[n], acc[m][n], 0, 0, 0);
    __syncthreads();
  }
#pragma unroll
  for (int m = 0; m < 4; ++m)
#pragma unroll
    for (int n = 0; n < 4; ++n)
#pragma unroll
      for (int r = 0; r < 4; ++r) {
        const size_t row = m0 + wr + m * 16 + lg * 4 + r;
        const size_t col = n0 + wc + n * 16 + lr;
        if (F32OUT)
          ((float*)Cv)[row * N + col] = acc[m][n][r];
        else
          ((u16*)Cv)[row * N + col] = f2bf(acc[m][n][r]);
      }
}

// ---------------------------------------------------------------------------
// hi/lo 3-term MFMA GEMM for q,k (f32-equivalent accuracy).
// ---------------------------------------------------------------------------
__global__ __launch_bounds__(256, 2) void gemm_hilo(
    const u16* __restrict__ Ah, const u16* __restrict__ Al,
    const u16* __restrict__ BhQ, const u16* __restrict__ BlQ,
    u16* __restrict__ ChQ, u16* __restrict__ ClQ,
    const u16* __restrict__ BhK, const u16* __restrict__ BlK,
    u16* __restrict__ ChK, u16* __restrict__ ClK, int K) {
  const bool isQ = (blockIdx.x == 0);
  const u16* Bh = isQ ? BhQ : BhK;
  const u16* Bl = isQ ? BlQ : BlK;
  u16* Ch = isQ ? ChQ : ChK;
  u16* Cl = isQ ? ClQ : ClK;
  const float scale = isQ ? 11.31370849898476f : 1.0f;
  __shared__ __align__(16) u16 Ahs[64 * 32], Als[64 * 32];
  __shared__ __align__(16) u16 Bhs[128 * 32], Bls[128 * 32];
  const int tid = threadIdx.x;
  const int w = tid >> 6, l = tid & 63;
  const int lr = l & 15, lg = l >> 4;
  const int m0 = blockIdx.y * 64;
  const int wc = w * 32;

  f32x4 acc[4][2];
#pragma unroll
  for (int m = 0; m < 4; ++m)
#pragma unroll
    for (int n = 0; n < 2; ++n) {
      f32x4 z = {0.f, 0.f, 0.f, 0.f};
      acc[m][n] = z;
    }

  const int arow = w * 16 + (l >> 2);
  const int brow0 = (w * 2 + 0) * 16 + (l >> 2);
  const int brow1 = (w * 2 + 1) * 16 + (l >> 2);
  const int scol = (l & 3) * 8;

  for (int kt = 0; kt < K; kt += 32) {
    gload_lds16(Ah + (size_t)(m0 + arow) * K + kt + scol, (char*)Ahs + w * 1024);
    gload_lds16(Al + (size_t)(m0 + arow) * K + kt + scol, (char*)Als + w * 1024);
    gload_lds16(Bh + (size_t)brow0 * K + kt + scol, (char*)Bhs + (w * 2 + 0) * 1024);
    gload_lds16(Bh + (size_t)brow1 * K + kt + scol, (char*)Bhs + (w * 2 + 1) * 1024);
    gload_lds16(Bl + (size_t)brow0 * K + kt + scol, (char*)Bls + (w * 2 + 0) * 1024);
    gload_lds16(Bl + (size_t)brow1 * K + kt + scol, (char*)Bls + (w * 2 + 1) * 1024);
    __syncthreads();
    bf16x8 afh[4], afl[4], bfh[2], bfl[2];
#pragma unroll
    for (int m = 0; m < 4; ++m) {
      afh[m] = *(const bf16x8*)((char*)Ahs + (m * 16 + lr) * 64 + lg * 16);
      afl[m] = *(const bf16x8*)((char*)Als + (m * 16 + lr) * 64 + lg * 16);
    }
#pragma unroll
    for (int n = 0; n < 2; ++n) {
      bfh[n] = *(const bf16x8*)((char*)Bhs + (wc + n * 16 + lr) * 64 + lg * 16);
      bfl[n] = *(const bf16x8*)((char*)Bls + (wc + n * 16 + lr) * 64 + lg * 16);
    }
#pragma unroll
    for (int m = 0; m < 4; ++m)
#pragma unroll
      for (int n = 0; n < 2; ++n) {
        acc[m][n] = __builtin_amdgcn_mfma_f32_16x16x32_bf16(afh[m], bfh[n], acc[m][n], 0, 0, 0);
        acc[m][n] = __builtin_amdgcn_mfma_f32_16x16x32_bf16(afh[m], bfl[n], acc[m][n], 0, 0, 0);
        acc[m][n] = __builtin_amdgcn_mfma_f32_16x16x32_bf16(afl[m], bfh[n], acc[m][n], 0, 0, 0);
      }
    __syncthreads();
  }
#pragma unroll
  for (int m = 0; m < 4; ++m)
#pragma unroll
    for (int n = 0; n < 2; ++n)
#pragma unroll
      for (int r = 0; r < 4; ++r) {
        const size_t row = m0 + m * 16 + lg * 4 + r;
        const size_t col = wc + n * 16 + lr;
        const float v = acc[m][n][r] * scale;
        const u16 h = f2bf(v);
        Ch[row * 128 + col] = h;
        Cl[row * 128 + col] = f2bf(v - bf2f(h));
      }
}

// ---------------------------------------------------------------------------
__global__ __launch_bounds__(256) void cvt_bf16(const float* __restrict__ in,
                                                u16* __restrict__ out) {
  const size_t idx = (size_t)blockIdx.x * 256 + threadIdx.x;
  const float4 a = ((const float4*)in)[idx * 2];
  const float4 b = ((const float4*)in)[idx * 2 + 1];
  u16x8 o;
  o[0] = f2bf(a.x); o[1] = f2bf(a.y); o[2] = f2bf(a.z); o[3] = f2bf(a.w);
  o[4] = f2bf(b.x); o[5] = f2bf(b.y); o[6] = f2bf(b.z); o[7] = f2bf(b.w);
  ((u16x8*)out)[idx] = o;
}

__global__ __launch_bounds__(256) void split_hl(const float* __restrict__ in,
                                                u16* __restrict__ hi,
                                                u16* __restrict__ lo) {
  const size_t idx = (size_t)blockIdx.x * 256 + threadIdx.x;
  const float4 v = ((const float4*)in)[idx];
  float f[4] = {v.x, v.y, v.z, v.w};
  u16 h[4], g[4];
#pragma unroll
  for (int i = 0; i < 4; ++i) {
    h[i] = f2bf(f[i]);
    g[i] = f2bf(f[i] - bf2f(h[i]));
  }
  ushort4 hv; hv.x = h[0]; hv.y = h[1]; hv.z = h[2]; hv.w = h[3];
  ushort4 gv; gv.x = g[0]; gv.y = g[1]; gv.z = g[2]; gv.w = g[3];
  ((ushort4*)hi)[idx] = hv;
  ((ushort4*)lo)[idx] = gv;
}

// ---------------------------------------------------------------------------
// repack k hi/lo row-major [8192][128] -> MFMA-fragment-tiled (1 KB frags).
// ---------------------------------------------------------------------------
__global__ __launch_bounds__(256) void repack_k(const u16* __restrict__ krh,
                                                const u16* __restrict__ krl,
                                                u16* __restrict__ khT,
                                                u16* __restrict__ klT) {
  const int gid = blockIdx.x * 256 + threadIdx.x;
  const int f = gid >> 6, l = gid & 63;
  const int fn = f >> 2, fk = f & 3;
  const size_t src = (size_t)(fn * 16 + (l & 15)) * 128 + fk * 32 + (l >> 4) * 8;
  *(u16x8*)(khT + (size_t)f * 512 + l * 8) = *(const u16x8*)(krh + src);
  *(u16x8*)(klT + (size_t)f * 512 + l * 8) = *(const u16x8*)(krl + src);
}

__global__ __launch_bounds__(256) void repack_vt(const u16* __restrict__ vr,
                                                 u16* __restrict__ vt) {
  const int gid = blockIdx.x * 256 + threadIdx.x;
  const int f = gid >> 6, l = gid & 63;
  const int fn = f >> 8, fk = f & 255;
  const size_t src = (size_t)(fn * 16 + (l & 15)) * 8192 + fk * 32 + (l >> 4) * 8;
  *(u16x8*)(vt + (size_t)f * 512 + l * 8) = *(const u16x8*)(vr + src);
}

// ---------------------------------------------------------------------------
// MFMA flash attention v2.
// grid = (2 halves, 128 q-blocks) x 512 threads (8 waves).
// Block (h, qb): q-rows qb*64..+63, v-cols h*512..+511.  KVBLK=128.
// Q hi/lo in XOR-swizzled LDS; K frags in regs (prefetched after scores);
// V 2-deep register ping-pong; scores 3-MFMA hi/lo; online softmax in LDS.
// ---------------------------------------------------------------------------
__global__ __launch_bounds__(512) __attribute__((amdgpu_waves_per_eu(2, 2)))
void flash_attn_mfma(const u16* __restrict__ qh, const u16* __restrict__ ql,
                     const u16* __restrict__ khT, const u16* __restrict__ klT,
                     const u16* __restrict__ vt, float* __restrict__ sa) {
  __shared__ __align__(16) u16 Qs[2 * 8192];  // hi|lo, 64x128 swizzled (32 KB)
  __shared__ float S[64 * 132];               // 33.8 KB
  __shared__ __align__(16) u16 P[64 * 128];   // 16 KB
  __shared__ float mrun[64], lrun[64], facl[64];
  const int tid = threadIdx.x;
  const int w = tid >> 6, l = tid & 63;
  const int lr = l & 15, lg = l >> 4;
  const int q0 = blockIdx.y * 64;
  const int half = blockIdx.x;  // v-col half

  {  // stage Q hi/lo into swizzled LDS
#pragma unroll
    for (int i = 0; i < 2; ++i) {
      const int e = i * 512 + tid;  // 0..1023
      const int row = e >> 4, c16 = e & 15;
      const u16x8 hv = *(const u16x8*)(qh + (size_t)(q0 + row) * 128 + c16 * 8);
      const u16x8 lv = *(const u16x8*)(ql + (size_t)(q0 + row) * 128 + c16 * 8);
      const int b = (row * 256 + c16 * 16) ^ ((row & 7) << 4);
      *(u16x8*)((char*)Qs + b) = hv;
      *(u16x8*)((char*)Qs + 16384 + b) = lv;
    }
  }
  if (tid < 64) { mrun[tid] = -INFINITY; lrun[tid] = 0.f; }

  f32x4 acc[4][4];  // 64 VGPR: 4 m-tiles x 4 n-tiles (wave's 64 cols)
#pragma unroll
  for (int mt = 0; mt < 4; ++mt)
#pragma unroll
    for (int nt = 0; nt < 4; ++nt) {
      f32x4 z = {0.f, 0.f, 0.f, 0.f};
      acc[mt][nt] = z;
    }

  bf16x8 kfh[4], kfl[4];
#pragma unroll
  for (int ks = 0; ks < 4; ++ks) {
    kfh[ks] = *(const bf16x8*)(khT + ((size_t)w * 4 + ks) * 512 + l * 8);
    kfl[ks] = *(const bf16x8*)(klT + ((size_t)w * 4 + ks) * 512 + l * 8);
  }
  __syncthreads();

  const int vcol0 = half * 32 + w * 4;  // v-frag column-tile base for this wave

  for (int t = 0; t < 64; ++t) {
    const int c = t * 4;
    // ---- scores: wave w -> S[0..63][w*16..w*16+15] ----
    f32x4 sf[4];
#pragma unroll
    for (int mt = 0; mt < 4; ++mt) {
      f32x4 z = {0.f, 0.f, 0.f, 0.f};
      sf[mt] = z;
    }
    __builtin_amdgcn_s_setprio(1);
#pragma unroll
    for (int ks = 0; ks < 4; ++ks)
#pragma unroll
      for (int mt = 0; mt < 4; ++mt) {
        const int row = mt * 16 + lr;
        const int b = (row * 256 + ks * 64 + lg * 16) ^ ((lr & 7) << 4);
        const bf16x8 qfh = *(const bf16x8*)((char*)Qs + b);
        const bf16x8 qfl = *(const bf16x8*)((char*)Qs + 16384 + b);
        sf[mt] = __builtin_amdgcn_mfma_f32_16x16x32_bf16(qfh, kfh[ks], sf[mt], 0, 0, 0);
        sf[mt] = __builtin_amdgcn_mfma_f32_16x16x32_bf16(qfh, kfl[ks], sf[mt], 0, 0, 0);
        sf[mt] = __builtin_amdgcn_mfma_f32_16x16x32_bf16(qfl, kfh[ks], sf[mt], 0, 0, 0);
      }
    __builtin_amdgcn_s_setprio(0);
    // ---- early issue: K(t+1) + V(ks0) loads land during softmax ----
    if (t < 63) {
#pragma unroll
      for (int ks = 0; ks < 4; ++ks) {
        kfh[ks] = *(const bf16x8*)(khT + ((size_t)((t + 1) * 8 + w) * 4 + ks) * 512 + l * 8);
        kfl[ks] = *(const bf16x8*)(klT + ((size_t)((t + 1) * 8 + w) * 4 + ks) * 512 + l * 8);
      }
    }
    bf16x8 vA[4], vB[4];
#pragma unroll
    for (int nt = 0; nt < 4; ++nt)
      vA[nt] = *(const bf16x8*)(vt + ((size_t)(vcol0 + nt) * 256 + c + 0) * 512 + l * 8);
#pragma unroll
    for (int mt = 0; mt < 4; ++mt)
#pragma unroll
      for (int r = 0; r < 4; ++r)
        S[(mt * 16 + lg * 4 + r) * 132 + w * 16 + lr] = sf[mt][r];
    __syncthreads();

    // ---- online softmax: wave w -> rows w*8..w*8+7, 2 cols/lane ----
    {
      float p0[8], p1[8], mx[8];
#pragma unroll
      for (int qq = 0; qq < 8; ++qq) {
        const float2 p = *(const float2*)&S[(w * 8 + qq) * 132 + 2 * l];
        p0[qq] = p.x; p1[qq] = p.y;
        mx[qq] = fmaxf(p.x, p.y);
      }
#pragma unroll
      for (int off = 32; off; off >>= 1)
#pragma unroll
        for (int qq = 0; qq < 8; ++qq) mx[qq] = fmaxf(mx[qq], __shfl_xor(mx[qq], off));
      float mo[8], mn[8], sm[8], e0[8], e1[8];
#pragma unroll
      for (int qq = 0; qq < 8; ++qq) {
        mo[qq] = mrun[w * 8 + qq];
        mn[qq] = fmaxf(mo[qq], mx[qq]);
        e0[qq] = __expf(p0[qq] - mn[qq]);
        e1[qq] = __expf(p1[qq] - mn[qq]);
        sm[qq] = e0[qq] + e1[qq];
      }
#pragma unroll
      for (int off = 32; off; off >>= 1)
#pragma unroll
        for (int qq = 0; qq < 8; ++qq) sm[qq] += __shfl_xor(sm[qq], off);
#pragma unroll
      for (int qq = 0; qq < 8; ++qq) {
        const int r = w * 8 + qq;
        const uint pu = ((uint)f2bf(e1[qq]) << 16) | f2bf(e0[qq]);
        *(uint*)((char*)P + ((r * 256 + l * 4) ^ ((r & 7) << 4))) = pu;
        if (l == 0) {
          const float fac = __expf(mo[qq] - mn[qq]);
          facl[r] = fac;
          mrun[r] = mn[qq];
          lrun[r] = lrun[r] * fac + sm[qq];
        }
      }
    }
    __syncthreads();

    // ---- rescale accumulators (skip when factor == 1) ----
#pragma unroll
    for (int mt = 0; mt < 4; ++mt)
#pragma unroll
      for (int r = 0; r < 4; ++r) {
        const float f = facl[mt * 16 + lg * 4 + r];
        if (f != 1.0f) {
#pragma unroll
          for (int nt = 0; nt < 4; ++nt) acc[mt][nt][r] *= f;
        }
      }

    // ---- PV: 2-deep register ping-pong over ks ----
#pragma unroll
    for (int ks = 0; ks < 4; ++ks) {
      bf16x8* nxt = (ks & 1) ? vA : vB;
      if (ks < 3) {
#pragma unroll
        for (int nt = 0; nt < 4; ++nt)
          nxt[nt] = *(const bf16x8*)(vt + ((size_t)(vcol0 + nt) * 256 + c + ks + 1) * 512 + l * 8);
      }
      const bf16x8* cur = (ks & 1) ? vB : vA;
      bf16x8 pf[4];
#pragma unroll
      for (int mt = 0; mt < 4; ++mt) {
        const int row = mt * 16 + lr;
        pf[mt] = *(const bf16x8*)((char*)P + ((row * 256 + ks * 64 + lg * 16) ^ ((lr & 7) << 4)));
      }
      __builtin_amdgcn_s_setprio(1);
#pragma unroll
      for (int mt = 0; mt < 4; ++mt)
#pragma unroll
        for (int nt = 0; nt < 4; ++nt)
          acc[mt][nt] = __builtin_amdgcn_mfma_f32_16x16x32_bf16(pf[mt], cur[nt], acc[mt][nt], 0, 0, 0);
      __builtin_amdgcn_s_setprio(0);
    }
  }
  // ---- epilogue ----
#pragma unroll
  for (int mt = 0; mt < 4; ++mt)
#pragma unroll
    for (int r = 0; r < 4; ++r) {
      const int row = mt * 16 + lg * 4 + r;
      const float inv = 1.0f / lrun[row];
#pragma unroll
      for (int nt = 0; nt < 4; ++nt)
        sa[(size_t)(q0 + row) * 1024 + half * 512 + w * 64 + nt * 16 + lr] =
            acc[mt][nt][r] * inv;
    }
}

// ---------------------------------------------------------------------------
// out(f32) = LayerNorm(a + b) over last dim 1024. Safe with o == b.
// ---------------------------------------------------------------------------
__global__ __launch_bounds__(256) void ln_add(const float* __restrict__ a,
                                              const float* __restrict__ b,
                                              float* __restrict__ o) {
  const int row = blockIdx.x;
  const int tid = threadIdx.x;
  const size_t base = (size_t)row * 256 + tid;
  const float4 av = ((const float4*)a)[base];
  const float4 bv = ((const float4*)b)[base];
  float4 y;
  y.x = av.x + bv.x; y.y = av.y + bv.y;
  y.z = av.z + bv.z; y.w = av.w + bv.w;
  float s1 = y.x + y.y + y.z + y.w;
  float s2 = y.x * y.x + y.y * y.y + y.z * y.z + y.w * y.w;
#pragma unroll
  for (int off = 32; off > 0; off >>= 1) {
    s1 += __shfl_xor(s1, off);
    s2 += __shfl_xor(s2, off);
  }
  __shared__ float r1[4];
  __shared__ float r2[4];
  if ((tid & 63) == 0) { r1[tid >> 6] = s1; r2[tid >> 6] = s2; }
  __syncthreads();
  s1 = r1[0] + r1[1] + r1[2] + r1[3];
  s2 = r2[0] + r2[1] + r2[2] + r2[3];
  const float mu = s1 * (1.0f / 1024.0f);
  const float var = s2 * (1.0f / 1024.0f) - mu * mu;
  const float rs = rsqrtf(var + 1e-5f);
  float4 ov;
  ov.x = (y.x - mu) * rs; ov.y = (y.y - mu) * rs;
  ov.z = (y.z - mu) * rs; ov.w = (y.w - mu) * rs;
  ((float4*)o)[base] = ov;
}

__global__ __launch_bounds__(256) void ln_add_bf16(const float* __restrict__ a,
                                                   const float* __restrict__ b,
                                                   u16* __restrict__ o) {
  const int row = blockIdx.x;
  const int tid = threadIdx.x;
  const size_t base = (size_t)row * 256 + tid;
  const float4 av = ((const float4*)a)[base];
  const float4 bv = ((const float4*)b)[base];
  float4 y;
  y.x = av.x + bv.x; y.y = av.y + bv.y;
  y.z = av.z + bv.z; y.w = av.w + bv.w;
  float s1 = y.x + y.y + y.z + y.w;
  float s2 = y.x * y.x + y.y * y.y + y.z * y.z + y.w * y.w;
#pragma unroll
  for (int off = 32; off > 0; off >>= 1) {
    s1 += __shfl_xor(s1, off);
    s2 += __shfl_xor(s2, off);
  }
  __shared__ float r1[4];
  __shared__ float r2[4];
  if ((tid & 63) == 0) { r1[tid >> 6] = s1; r2[tid >> 6] = s2; }
  __syncthreads();
  s1 = r1[0] + r1[1] + r1[2] + r1[3];
  s2 = r2[0] + r2[1] + r2[2] + r2[3];
  const float mu = s1 * (1.0f / 1024.0f);
  const float var = s2 * (1.0f / 1024.0f) - mu * mu;
  const float rs = rsqrtf(var + 1e-5f);
  ushort4 ov;
  ov.x = f2bf((y.x - mu) * rs); ov.y = f2bf((y.y - mu) * rs);
  ov.z = f2bf((y.z - mu) * rs); ov.w = f2bf((y.w - mu) * rs);
  ((ushort4*)o)[base] = ov;
}

// ---------------------------------------------------------------------------
extern "C" void kernel_launch(void* const* d_in, const int* in_sizes, int n_in,
                              void* d_out, int out_size, void* d_ws, size_t ws_size,
                              hipStream_t stream) {
  const float* x  = (const float*)d_in[0];
  const float* Wq = (const float*)d_in[1];
  const float* Wk = (const float*)d_in[2];
  const float* Wv = (const float*)d_in[3];
  const float* Wl = (const float*)d_in[4];
  float* out = (float*)d_out;

  char* w8 = (char*)d_ws;
  u16* xh  = (u16*)(w8 + (0ull << 20));
  u16* xl  = (u16*)(w8 + (16ull << 20));
  u16* khT = (u16*)(w8 + (16ull << 20));
  u16* klT = (u16*)(w8 + (18ull << 20));
  u16* vtr = (u16*)(w8 + (32ull << 20));
  u16* qh  = (u16*)(w8 + (32ull << 20));
  u16* ql  = (u16*)(w8 + (34ull << 20));
  u16* krh = (u16*)(w8 + (36ull << 20));
  u16* krl = (u16*)(w8 + (38ull << 20));
  u16* hb  = (u16*)(w8 + (32ull << 20));
  u16* vtt = (u16*)(w8 + (48ull << 20));
  float* sa = (float*)(w8 + (64ull << 20));
  u16* wqh = (u16*)(w8 + (92ull << 20));
  u16* wql = (u16*)(w8 + (92ull << 20) + (256ull << 10));
  u16* wkh = (u16*)(w8 + (92ull << 20) + (512ull << 10));
  u16* wkl = (u16*)(w8 + (92ull << 20) + (768ull << 10));
  u16* Wvb = (u16*)(w8 + (96ull << 20));
  u16* Wlb = (u16*)(w8 + (98ull << 20));

  split_hl<<<8192, 256, 0, stream>>>(x, xh, xl);
  cvt_bf16<<<512, 256, 0, stream>>>(Wv, Wvb);
  cvt_bf16<<<512, 256, 0, stream>>>(Wl, Wlb);
  gemm_mfma<0><<<dim3(64, 8), 256, 0, stream>>>(Wvb, xh, (void*)vtr, D_IN, N_TOK, D_IN);
  repack_vt<<<4096, 256, 0, stream>>>(vtr, vtt);
  split_hl<<<128, 256, 0, stream>>>(Wq, wqh, wql);
  split_hl<<<128, 256, 0, stream>>>(Wk, wkh, wkl);
  gemm_hilo<<<dim3(2, 128), 256, 0, stream>>>(xh, xl, wqh, wql, qh, ql,
                                              wkh, wkl, krh, krl, D_IN);
  repack_k<<<512, 256, 0, stream>>>(krh, krl, khT, klT);
  flash_attn_mfma<<<dim3(2, 128), 512, 0, stream>>>(qh, ql, khT, klT, vtt, sa);
  ln_add_bf16<<<N_TOK, 256, 0, stream>>>(x, sa, hb);
  gemm_mfma<1><<<dim3(8, 64), 256, 0, stream>>>(hb, Wlb, (void*)out, N_TOK, D_IN, D_IN);
  ln_add<<<N_TOK, 256, 0, stream>>>(sa, out, out);
}

// Round 6
// 397.992 us; speedup vs baseline: 12.9779x; 1.3826x over previous
//
#include <hip/hip_runtime.h>
#include <hip/hip_bf16.h>
#include <math.h>

#define N_TOK 8192
#define D_IN  1024
#define D_QK  128

typedef short bf16x8 __attribute__((ext_vector_type(8)));
typedef float f32x4 __attribute__((ext_vector_type(4)));
typedef unsigned short u16;
typedef u16 u16x8 __attribute__((ext_vector_type(8)));

static __device__ __forceinline__ u16 f2bf(float f) {
  __hip_bfloat16 b = __float2bfloat16(f);
  return *(u16*)&b;
}
static __device__ __forceinline__ float bf2f(u16 u) {
  __hip_bfloat16 b = *(__hip_bfloat16*)&u;
  return __bfloat162float(b);
}

static __device__ __forceinline__ void gload_lds16(const void* g, void* lds) {
  __builtin_amdgcn_global_load_lds(
      (const __attribute__((address_space(1))) unsigned int*)g,
      (__attribute__((address_space(3))) unsigned int*)lds, 16, 0, 0);
}

// ---------------------------------------------------------------------------
// bf16 MFMA GEMM: C[M][N] = A[M][K] * B[N][K]^T, 128x128 tile, BK=32.
// ---------------------------------------------------------------------------
template <int F32OUT>
__global__ __launch_bounds__(256, 2) void gemm_mfma(const u16* __restrict__ A,
                                                    const u16* __restrict__ B,
                                                    void* __restrict__ Cv,
                                                    int M, int N, int K) {
  __shared__ __align__(16) u16 As[128 * 32];
  __shared__ __align__(16) u16 Bs[128 * 32];
  const int tid = threadIdx.x;
  const int w = tid >> 6, l = tid & 63;
  const int lr = l & 15, lg = l >> 4;
  const int m0 = blockIdx.y * 128, n0 = blockIdx.x * 128;
  const int wr = (w >> 1) * 64, wc = (w & 1) * 64;

  f32x4 acc[4][4];
#pragma unroll
  for (int m = 0; m < 4; ++m)
#pragma unroll
    for (int n = 0; n < 4; ++n) {
      f32x4 z = {0.f, 0.f, 0.f, 0.f};
      acc[m][n] = z;
    }

  const int ldsb0 = (w * 2 + 0) * 1024;
  const int ldsb1 = (w * 2 + 1) * 1024;
  const int srow0 = (w * 2 + 0) * 16 + (l >> 2);
  const int srow1 = (w * 2 + 1) * 16 + (l >> 2);
  const int scol = (l & 3) * 8;

  for (int kt = 0; kt < K; kt += 32) {
    gload_lds16(A + (size_t)(m0 + srow0) * K + kt + scol, (char*)As + ldsb0);
    gload_lds16(A + (size_t)(m0 + srow1) * K + kt + scol, (char*)As + ldsb1);
    gload_lds16(B + (size_t)(n0 + srow0) * K + kt + scol, (char*)Bs + ldsb0);
    gload_lds16(B + (size_t)(n0 + srow1) * K + kt + scol, (char*)Bs + ldsb1);
    __syncthreads();
    bf16x8 af[4], bfr[4];
#pragma unroll
    for (int m = 0; m < 4; ++m)
      af[m] = *(const bf16x8*)((char*)As + (wr + m * 16 + lr) * 64 + lg * 16);
#pragma unroll
    for (int n = 0; n < 4; ++n)
      bfr[n] = *(const bf16x8*)((char*)Bs + (wc + n * 16 + lr) * 64 + lg * 16);
#pragma unroll
    for (int m = 0; m < 4; ++m)
#pragma unroll
      for (int n = 0; n < 4; ++n)
        acc[m][n] = __builtin_amdgcn_mfma_f32_16x16x32_bf16(af[m], bfr[n], acc[m][n], 0, 0, 0);
    __syncthreads();
  }
#pragma unroll
  for (int m = 0; m < 4; ++m)
#pragma unroll
    for (int n = 0; n < 4; ++n)
#pragma unroll
      for (int r = 0; r < 4; ++r) {
        const size_t row = m0 + wr + m * 16 + lg * 4 + r;
        const size_t col = n0 + wc + n * 16 + lr;
        if (F32OUT)
          ((float*)Cv)[row * N + col] = acc[m][n][r];
        else
          ((u16*)Cv)[row * N + col] = f2bf(acc[m][n][r]);
      }
}

// ---------------------------------------------------------------------------
// hi/lo 3-term MFMA GEMM for q,k (f32-equivalent accuracy).
// ---------------------------------------------------------------------------
__global__ __launch_bounds__(256, 2) void gemm_hilo(
    const u16* __restrict__ Ah, const u16* __restrict__ Al,
    const u16* __restrict__ BhQ, const u16* __restrict__ BlQ,
    u16* __restrict__ ChQ, u16* __restrict__ ClQ,
    const u16* __restrict__ BhK, const u16* __restrict__ BlK,
    u16* __restrict__ ChK, u16* __restrict__ ClK, int K) {
  const bool isQ = (blockIdx.x == 0);
  const u16* Bh = isQ ? BhQ : BhK;
  const u16* Bl = isQ ? BlQ : BlK;
  u16* Ch = isQ ? ChQ : ChK;
  u16* Cl = isQ ? ClQ : ClK;
  const float scale = isQ ? 11.31370849898476f : 1.0f;
  __shared__ __align__(16) u16 Ahs[64 * 32], Als[64 * 32];
  __shared__ __align__(16) u16 Bhs[128 * 32], Bls[128 * 32];
  const int tid = threadIdx.x;
  const int w = tid >> 6, l = tid & 63;
  const int lr = l & 15, lg = l >> 4;
  const int m0 = blockIdx.y * 64;
  const int wc = w * 32;

  f32x4 acc[4][2];
#pragma unroll
  for (int m = 0; m < 4; ++m)
#pragma unroll
    for (int n = 0; n < 2; ++n) {
      f32x4 z = {0.f, 0.f, 0.f, 0.f};
      acc[m][n] = z;
    }

  const int arow = w * 16 + (l >> 2);
  const int brow0 = (w * 2 + 0) * 16 + (l >> 2);
  const int brow1 = (w * 2 + 1) * 16 + (l >> 2);
  const int scol = (l & 3) * 8;

  for (int kt = 0; kt < K; kt += 32) {
    gload_lds16(Ah + (size_t)(m0 + arow) * K + kt + scol, (char*)Ahs + w * 1024);
    gload_lds16(Al + (size_t)(m0 + arow) * K + kt + scol, (char*)Als + w * 1024);
    gload_lds16(Bh + (size_t)brow0 * K + kt + scol, (char*)Bhs + (w * 2 + 0) * 1024);
    gload_lds16(Bh + (size_t)brow1 * K + kt + scol, (char*)Bhs + (w * 2 + 1) * 1024);
    gload_lds16(Bl + (size_t)brow0 * K + kt + scol, (char*)Bls + (w * 2 + 0) * 1024);
    gload_lds16(Bl + (size_t)brow1 * K + kt + scol, (char*)Bls + (w * 2 + 1) * 1024);
    __syncthreads();
    bf16x8 afh[4], afl[4], bfh[2], bfl[2];
#pragma unroll
    for (int m = 0; m < 4; ++m) {
      afh[m] = *(const bf16x8*)((char*)Ahs + (m * 16 + lr) * 64 + lg * 16);
      afl[m] = *(const bf16x8*)((char*)Als + (m * 16 + lr) * 64 + lg * 16);
    }
#pragma unroll
    for (int n = 0; n < 2; ++n) {
      bfh[n] = *(const bf16x8*)((char*)Bhs + (wc + n * 16 + lr) * 64 + lg * 16);
      bfl[n] = *(const bf16x8*)((char*)Bls + (wc + n * 16 + lr) * 64 + lg * 16);
    }
#pragma unroll
    for (int m = 0; m < 4; ++m)
#pragma unroll
      for (int n = 0; n < 2; ++n) {
        acc[m][n] = __builtin_amdgcn_mfma_f32_16x16x32_bf16(afh[m], bfh[n], acc[m][n], 0, 0, 0);
        acc[m][n] = __builtin_amdgcn_mfma_f32_16x16x32_bf16(afh[m], bfl[n], acc[m][n], 0, 0, 0);
        acc[m][n] = __builtin_amdgcn_mfma_f32_16x16x32_bf16(afl[m], bfh[n], acc[m][n], 0, 0, 0);
      }
    __syncthreads();
  }
#pragma unroll
  for (int m = 0; m < 4; ++m)
#pragma unroll
    for (int n = 0; n < 2; ++n)
#pragma unroll
      for (int r = 0; r < 4; ++r) {
        const size_t row = m0 + m * 16 + lg * 4 + r;
        const size_t col = wc + n * 16 + lr;
        const float v = acc[m][n][r] * scale;
        const u16 h = f2bf(v);
        Ch[row * 128 + col] = h;
        Cl[row * 128 + col] = f2bf(v - bf2f(h));
      }
}

// ---------------------------------------------------------------------------
__global__ __launch_bounds__(256) void cvt_bf16(const float* __restrict__ in,
                                                u16* __restrict__ out) {
  const size_t idx = (size_t)blockIdx.x * 256 + threadIdx.x;
  const float4 a = ((const float4*)in)[idx * 2];
  const float4 b = ((const float4*)in)[idx * 2 + 1];
  u16x8 o;
  o[0] = f2bf(a.x); o[1] = f2bf(a.y); o[2] = f2bf(a.z); o[3] = f2bf(a.w);
  o[4] = f2bf(b.x); o[5] = f2bf(b.y); o[6] = f2bf(b.z); o[7] = f2bf(b.w);
  ((u16x8*)out)[idx] = o;
}

__global__ __launch_bounds__(256) void split_hl(const float* __restrict__ in,
                                                u16* __restrict__ hi,
                                                u16* __restrict__ lo) {
  const size_t idx = (size_t)blockIdx.x * 256 + threadIdx.x;
  const float4 v = ((const float4*)in)[idx];
  float f[4] = {v.x, v.y, v.z, v.w};
  u16 h[4], g[4];
#pragma unroll
  for (int i = 0; i < 4; ++i) {
    h[i] = f2bf(f[i]);
    g[i] = f2bf(f[i] - bf2f(h[i]));
  }
  ushort4 hv; hv.x = h[0]; hv.y = h[1]; hv.z = h[2]; hv.w = h[3];
  ushort4 gv; gv.x = g[0]; gv.y = g[1]; gv.z = g[2]; gv.w = g[3];
  ((ushort4*)hi)[idx] = hv;
  ((ushort4*)lo)[idx] = gv;
}

// ---------------------------------------------------------------------------
// repack k hi/lo row-major [8192][128] -> MFMA-fragment-tiled (1 KB frags).
// ---------------------------------------------------------------------------
__global__ __launch_bounds__(256) void repack_k(const u16* __restrict__ krh,
                                                const u16* __restrict__ krl,
                                                u16* __restrict__ khT,
                                                u16* __restrict__ klT) {
  const int gid = blockIdx.x * 256 + threadIdx.x;
  const int f = gid >> 6, l = gid & 63;
  const int fn = f >> 2, fk = f & 3;
  const size_t src = (size_t)(fn * 16 + (l & 15)) * 128 + fk * 32 + (l >> 4) * 8;
  *(u16x8*)(khT + (size_t)f * 512 + l * 8) = *(const u16x8*)(krh + src);
  *(u16x8*)(klT + (size_t)f * 512 + l * 8) = *(const u16x8*)(krl + src);
}

__global__ __launch_bounds__(256) void repack_vt(const u16* __restrict__ vr,
                                                 u16* __restrict__ vt) {
  const int gid = blockIdx.x * 256 + threadIdx.x;
  const int f = gid >> 6, l = gid & 63;
  const int fn = f >> 8, fk = f & 255;
  const size_t src = (size_t)(fn * 16 + (l & 15)) * 8192 + fk * 32 + (l >> 4) * 8;
  *(u16x8*)(vt + (size_t)f * 512 + l * 8) = *(const u16x8*)(vr + src);
}

// ---------------------------------------------------------------------------
// MFMA flash attention v3: swapped-operand scores (S^T = mfma(K,Q)) so the
// k-axis is lane-local -> in-register softmax (T12 structure).
// grid = (2 halves, 128 q-blocks) x 512 threads (8 waves).
// Block (h, qb): q-rows qb*64..+63, v-cols h*512..+511.  KVBLK=128.
// Wave w: scores for k-slice [w*16, w*16+16) x all 64 q; PV cols w*64..+63.
// m (running max) and per-wave-partial l live in REGISTERS; cross-wave max
// via tiny pmax[64][8] LDS; l combined once at the end.
// ---------------------------------------------------------------------------
__global__ __launch_bounds__(512) __attribute__((amdgpu_waves_per_eu(2, 2)))
void flash_attn_mfma(const u16* __restrict__ qh, const u16* __restrict__ ql,
                     const u16* __restrict__ khT, const u16* __restrict__ klT,
                     const u16* __restrict__ vt, float* __restrict__ sa) {
  __shared__ __align__(16) u16 Qs[2 * 8192];   // hi|lo, 64x128 swizzled (32 KB)
  __shared__ __align__(16) u16 P[64 * 128];    // 16 KB swizzled
  __shared__ __align__(16) float pmax[64][12]; // stride 48 B (16B-aligned rows)
  __shared__ __align__(16) float lpart[64][12];
  __shared__ __align__(16) float facl[64];
  const int tid = threadIdx.x;
  const int w = tid >> 6, l = tid & 63;
  const int lr = l & 15, lg = l >> 4;
  const int q0 = blockIdx.y * 64;
  const int half = blockIdx.x;

  {  // stage Q hi/lo into swizzled LDS
#pragma unroll
    for (int i = 0; i < 2; ++i) {
      const int e = i * 512 + tid;  // 0..1023
      const int row = e >> 4, c16 = e & 15;
      const u16x8 hv = *(const u16x8*)(qh + (size_t)(q0 + row) * 128 + c16 * 8);
      const u16x8 lv = *(const u16x8*)(ql + (size_t)(q0 + row) * 128 + c16 * 8);
      const int b = (row * 256 + c16 * 16) ^ ((row & 7) << 4);
      *(u16x8*)((char*)Qs + b) = hv;
      *(u16x8*)((char*)Qs + 16384 + b) = lv;
    }
  }

  // per-lane online-softmax state: rows mt*16+lr (4 rows per lane)
  float mrun4[4] = {-INFINITY, -INFINITY, -INFINITY, -INFINITY};
  float lrun4[4] = {0.f, 0.f, 0.f, 0.f};  // wave-partial (this wave's k-slices)

  f32x4 acc[4][4];
#pragma unroll
  for (int mt = 0; mt < 4; ++mt)
#pragma unroll
    for (int nt = 0; nt < 4; ++nt) {
      f32x4 z = {0.f, 0.f, 0.f, 0.f};
      acc[mt][nt] = z;
    }

  bf16x8 kfh[4], kfl[4];
#pragma unroll
  for (int ks = 0; ks < 4; ++ks) {
    kfh[ks] = *(const bf16x8*)(khT + ((size_t)w * 4 + ks) * 512 + l * 8);
    kfl[ks] = *(const bf16x8*)(klT + ((size_t)w * 4 + ks) * 512 + l * 8);
  }
  __syncthreads();

  const int vcol0 = half * 32 + w * 4;

  for (int t = 0; t < 64; ++t) {
    const int c = t * 4;
    // ---- scores (swapped): sfT[mt][r] = S^T[k = w*16+lg*4+r][q = mt*16+lr] ----
    f32x4 sfT[4];
#pragma unroll
    for (int mt = 0; mt < 4; ++mt) {
      f32x4 z = {0.f, 0.f, 0.f, 0.f};
      sfT[mt] = z;
    }
    __builtin_amdgcn_s_setprio(1);
#pragma unroll
    for (int ks = 0; ks < 4; ++ks)
#pragma unroll
      for (int mt = 0; mt < 4; ++mt) {
        const int b = ((mt * 16 + lr) * 256 + ks * 64 + lg * 16) ^ ((lr & 7) << 4);
        const bf16x8 qfh = *(const bf16x8*)((char*)Qs + b);
        const bf16x8 qfl = *(const bf16x8*)((char*)Qs + 16384 + b);
        sfT[mt] = __builtin_amdgcn_mfma_f32_16x16x32_bf16(kfh[ks], qfh, sfT[mt], 0, 0, 0);
        sfT[mt] = __builtin_amdgcn_mfma_f32_16x16x32_bf16(kfl[ks], qfh, sfT[mt], 0, 0, 0);
        sfT[mt] = __builtin_amdgcn_mfma_f32_16x16x32_bf16(kfh[ks], qfl, sfT[mt], 0, 0, 0);
      }
    __builtin_amdgcn_s_setprio(0);
    // ---- early issue: K(t+1) + V(ks0) (land during softmax) ----
    if (t < 63) {
#pragma unroll
      for (int ks = 0; ks < 4; ++ks) {
        kfh[ks] = *(const bf16x8*)(khT + ((size_t)((t + 1) * 8 + w) * 4 + ks) * 512 + l * 8);
        kfl[ks] = *(const bf16x8*)(klT + ((size_t)((t + 1) * 8 + w) * 4 + ks) * 512 + l * 8);
      }
    }
    bf16x8 vA[4], vB[4];
#pragma unroll
    for (int nt = 0; nt < 4; ++nt)
      vA[nt] = *(const bf16x8*)(vt + ((size_t)(vcol0 + nt) * 256 + c + 0) * 512 + l * 8);

    // ---- wave-slice max: lane-local over 4 k, then 4-lane-group shfl ----
    float wmax[4];
#pragma unroll
    for (int mt = 0; mt < 4; ++mt)
      wmax[mt] = fmaxf(fmaxf(sfT[mt][0], sfT[mt][1]), fmaxf(sfT[mt][2], sfT[mt][3]));
#pragma unroll
    for (int mt = 0; mt < 4; ++mt) {
      wmax[mt] = fmaxf(wmax[mt], __shfl_xor(wmax[mt], 16));
      wmax[mt] = fmaxf(wmax[mt], __shfl_xor(wmax[mt], 32));
    }
    if (lg == 0) {
#pragma unroll
      for (int mt = 0; mt < 4; ++mt) pmax[mt * 16 + lr][w] = wmax[mt];
    }
    __syncthreads();  // BAR1

    // ---- global max, fac, exp, pack P, wave-partial sum (all in regs) ----
    float mn4[4], fac4[4];
#pragma unroll
    for (int mt = 0; mt < 4; ++mt) {
      const int q = mt * 16 + lr;
      const f32x4 a = *(const f32x4*)&pmax[q][0];
      const f32x4 b = *(const f32x4*)&pmax[q][4];
      const float mx = fmaxf(fmaxf(fmaxf(a[0], a[1]), fmaxf(a[2], a[3])),
                             fmaxf(fmaxf(b[0], b[1]), fmaxf(b[2], b[3])));
      const float mn = fmaxf(mrun4[mt], mx);
      fac4[mt] = __expf(mrun4[mt] - mn);
      mn4[mt] = mn;
      mrun4[mt] = mn;
    }
    if (w == 0 && lg == 0) {
#pragma unroll
      for (int mt = 0; mt < 4; ++mt) facl[mt * 16 + lr] = fac4[mt];
    }
#pragma unroll
    for (int mt = 0; mt < 4; ++mt) {
      const float e0 = __expf(sfT[mt][0] - mn4[mt]);
      const float e1 = __expf(sfT[mt][1] - mn4[mt]);
      const float e2 = __expf(sfT[mt][2] - mn4[mt]);
      const float e3 = __expf(sfT[mt][3] - mn4[mt]);
      float tot = (e0 + e1) + (e2 + e3);
      tot += __shfl_xor(tot, 16);
      tot += __shfl_xor(tot, 32);
      lrun4[mt] = lrun4[mt] * fac4[mt] + tot;
      ushort4 pb;
      pb.x = f2bf(e0); pb.y = f2bf(e1); pb.z = f2bf(e2); pb.w = f2bf(e3);
      const int q = mt * 16 + lr;
      const int byte = (q * 256 + w * 32 + lg * 8) ^ ((lr & 7) << 4);
      *(ushort4*)((char*)P + byte) = pb;
    }
    __syncthreads();  // BAR2

    // ---- rescale accumulators ----
#pragma unroll
    for (int mt = 0; mt < 4; ++mt) {
      const f32x4 f4 = *(const f32x4*)&facl[mt * 16 + lg * 4];
#pragma unroll
      for (int rr = 0; rr < 4; ++rr) {
        const float f = f4[rr];
        if (f != 1.0f) {
#pragma unroll
          for (int nt = 0; nt < 4; ++nt) acc[mt][nt][rr] *= f;
        }
      }
    }

    // ---- PV: 2-deep register ping-pong over ks ----
#pragma unroll
    for (int ks = 0; ks < 4; ++ks) {
      bf16x8* nxt = (ks & 1) ? vA : vB;
      if (ks < 3) {
#pragma unroll
        for (int nt = 0; nt < 4; ++nt)
          nxt[nt] = *(const bf16x8*)(vt + ((size_t)(vcol0 + nt) * 256 + c + ks + 1) * 512 + l * 8);
      }
      const bf16x8* cur = (ks & 1) ? vB : vA;
      bf16x8 pf[4];
#pragma unroll
      for (int mt = 0; mt < 4; ++mt) {
        const int row = mt * 16 + lr;
        pf[mt] = *(const bf16x8*)((char*)P + ((row * 256 + ks * 64 + lg * 16) ^ ((lr & 7) << 4)));
      }
      __builtin_amdgcn_s_setprio(1);
#pragma unroll
      for (int mt = 0; mt < 4; ++mt)
#pragma unroll
        for (int nt = 0; nt < 4; ++nt)
          acc[mt][nt] = __builtin_amdgcn_mfma_f32_16x16x32_bf16(pf[mt], cur[nt], acc[mt][nt], 0, 0, 0);
      __builtin_amdgcn_s_setprio(0);
    }
  }
  // ---- combine wave-partial l, epilogue ----
  if (lg == 0) {
#pragma unroll
    for (int mt = 0; mt < 4; ++mt) lpart[mt * 16 + lr][w] = lrun4[mt];
  }
  __syncthreads();
#pragma unroll
  for (int mt = 0; mt < 4; ++mt)
#pragma unroll
    for (int rr = 0; rr < 4; ++rr) {
      const int row = mt * 16 + lg * 4 + rr;
      const f32x4 a = *(const f32x4*)&lpart[row][0];
      const f32x4 b = *(const f32x4*)&lpart[row][4];
      const float inv =
          1.0f / (((a[0] + a[1]) + (a[2] + a[3])) + ((b[0] + b[1]) + (b[2] + b[3])));
#pragma unroll
      for (int nt = 0; nt < 4; ++nt)
        sa[(size_t)(q0 + row) * 1024 + half * 512 + w * 64 + nt * 16 + lr] =
            acc[mt][nt][rr] * inv;
    }
}

// ---------------------------------------------------------------------------
// out(f32) = LayerNorm(a + b) over last dim 1024. Safe with o == b.
// ---------------------------------------------------------------------------
__global__ __launch_bounds__(256) void ln_add(const float* __restrict__ a,
                                              const float* __restrict__ b,
                                              float* __restrict__ o) {
  const int row = blockIdx.x;
  const int tid = threadIdx.x;
  const size_t base = (size_t)row * 256 + tid;
  const float4 av = ((const float4*)a)[base];
  const float4 bv = ((const float4*)b)[base];
  float4 y;
  y.x = av.x + bv.x; y.y = av.y + bv.y;
  y.z = av.z + bv.z; y.w = av.w + bv.w;
  float s1 = y.x + y.y + y.z + y.w;
  float s2 = y.x * y.x + y.y * y.y + y.z * y.z + y.w * y.w;
#pragma unroll
  for (int off = 32; off > 0; off >>= 1) {
    s1 += __shfl_xor(s1, off);
    s2 += __shfl_xor(s2, off);
  }
  __shared__ float r1[4];
  __shared__ float r2[4];
  if ((tid & 63) == 0) { r1[tid >> 6] = s1; r2[tid >> 6] = s2; }
  __syncthreads();
  s1 = r1[0] + r1[1] + r1[2] + r1[3];
  s2 = r2[0] + r2[1] + r2[2] + r2[3];
  const float mu = s1 * (1.0f / 1024.0f);
  const float var = s2 * (1.0f / 1024.0f) - mu * mu;
  const float rs = rsqrtf(var + 1e-5f);
  float4 ov;
  ov.x = (y.x - mu) * rs; ov.y = (y.y - mu) * rs;
  ov.z = (y.z - mu) * rs; ov.w = (y.w - mu) * rs;
  ((float4*)o)[base] = ov;
}

__global__ __launch_bounds__(256) void ln_add_bf16(const float* __restrict__ a,
                                                   const float* __restrict__ b,
                                                   u16* __restrict__ o) {
  const int row = blockIdx.x;
  const int tid = threadIdx.x;
  const size_t base = (size_t)row * 256 + tid;
  const float4 av = ((const float4*)a)[base];
  const float4 bv = ((const float4*)b)[base];
  float4 y;
  y.x = av.x + bv.x; y.y = av.y + bv.y;
  y.z = av.z + bv.z; y.w = av.w + bv.w;
  float s1 = y.x + y.y + y.z + y.w;
  float s2 = y.x * y.x + y.y * y.y + y.z * y.z + y.w * y.w;
#pragma unroll
  for (int off = 32; off > 0; off >>= 1) {
    s1 += __shfl_xor(s1, off);
    s2 += __shfl_xor(s2, off);
  }
  __shared__ float r1[4];
  __shared__ float r2[4];
  if ((tid & 63) == 0) { r1[tid >> 6] = s1; r2[tid >> 6] = s2; }
  __syncthreads();
  s1 = r1[0] + r1[1] + r1[2] + r1[3];
  s2 = r2[0] + r2[1] + r2[2] + r2[3];
  const float mu = s1 * (1.0f / 1024.0f);
  const float var = s2 * (1.0f / 1024.0f) - mu * mu;
  const float rs = rsqrtf(var + 1e-5f);
  ushort4 ov;
  ov.x = f2bf((y.x - mu) * rs); ov.y = f2bf((y.y - mu) * rs);
  ov.z = f2bf((y.z - mu) * rs); ov.w = f2bf((y.w - mu) * rs);
  ((ushort4*)o)[base] = ov;
}

// ---------------------------------------------------------------------------
extern "C" void kernel_launch(void* const* d_in, const int* in_sizes, int n_in,
                              void* d_out, int out_size, void* d_ws, size_t ws_size,
                              hipStream_t stream) {
  const float* x  = (const float*)d_in[0];
  const float* Wq = (const float*)d_in[1];
  const float* Wk = (const float*)d_in[2];
  const float* Wv = (const float*)d_in[3];
  const float* Wl = (const float*)d_in[4];
  float* out = (float*)d_out;

  char* w8 = (char*)d_ws;
  u16* xh  = (u16*)(w8 + (0ull << 20));
  u16* xl  = (u16*)(w8 + (16ull << 20));
  u16* khT = (u16*)(w8 + (16ull << 20));
  u16* klT = (u16*)(w8 + (18ull << 20));
  u16* vtr = (u16*)(w8 + (32ull << 20));
  u16* qh  = (u16*)(w8 + (32ull << 20));
  u16* ql  = (u16*)(w8 + (34ull << 20));
  u16* krh = (u16*)(w8 + (36ull << 20));
  u16* krl = (u16*)(w8 + (38ull << 20));
  u16* hb  = (u16*)(w8 + (32ull << 20));
  u16* vtt = (u16*)(w8 + (48ull << 20));
  float* sa = (float*)(w8 + (64ull << 20));
  u16* wqh = (u16*)(w8 + (92ull << 20));
  u16* wql = (u16*)(w8 + (92ull << 20) + (256ull << 10));
  u16* wkh = (u16*)(w8 + (92ull << 20) + (512ull << 10));
  u16* wkl = (u16*)(w8 + (92ull << 20) + (768ull << 10));
  u16* Wvb = (u16*)(w8 + (96ull << 20));
  u16* Wlb = (u16*)(w8 + (98ull << 20));

  split_hl<<<8192, 256, 0, stream>>>(x, xh, xl);
  cvt_bf16<<<512, 256, 0, stream>>>(Wv, Wvb);
  cvt_bf16<<<512, 256, 0, stream>>>(Wl, Wlb);
  gemm_mfma<0><<<dim3(64, 8), 256, 0, stream>>>(Wvb, xh, (void*)vtr, D_IN, N_TOK, D_IN);
  repack_vt<<<4096, 256, 0, stream>>>(vtr, vtt);
  split_hl<<<128, 256, 0, stream>>>(Wq, wqh, wql);
  split_hl<<<128, 256, 0, stream>>>(Wk, wkh, wkl);
  gemm_hilo<<<dim3(2, 128), 256, 0, stream>>>(xh, xl, wqh, wql, qh, ql,
                                              wkh, wkl, krh, krl, D_IN);
  repack_k<<<512, 256, 0, stream>>>(krh, krl, khT, klT);
  flash_attn_mfma<<<dim3(2, 128), 512, 0, stream>>>(qh, ql, khT, klT, vtt, sa);
  ln_add_bf16<<<N_TOK, 256, 0, stream>>>(x, sa, hb);
  gemm_mfma<1><<<dim3(8, 64), 256, 0, stream>>>(hb, Wlb, (void*)out, N_TOK, D_IN, D_IN);
  ln_add<<<N_TOK, 256, 0, stream>>>(sa, out, out);
}